// Round 1
// baseline (311.465 us; speedup 1.0000x reference)
//
#include <hip/hip_runtime.h>
#include <hip/hip_bf16.h>
#include <math.h>

typedef unsigned short u16;
typedef __bf16 bf16x8 __attribute__((ext_vector_type(8)));
typedef float f32x4 __attribute__((ext_vector_type(4)));
typedef u16 u16x8 __attribute__((ext_vector_type(8)));
typedef u16 u16x4 __attribute__((ext_vector_type(4)));

#define DM 1024
#define NH 16
#define HD 64
#define SL 2048
#define BB 2

__device__ __forceinline__ u16 f2bf(float f) {
  union { float f; unsigned u; } v; v.f = f;
  unsigned r = v.u + 0x7FFFu + ((v.u >> 16) & 1u);
  return (u16)(r >> 16);
}

// ---------------- conversion kernels ----------------
__global__ void cast_bf16(const float* __restrict__ in, u16* __restrict__ out, int n) {
  int i = (blockIdx.x * blockDim.x + threadIdx.x) * 8;
  if (i + 8 <= n) {
    float4 a = *(const float4*)(in + i);
    float4 b = *(const float4*)(in + i + 4);
    u16x8 o;
    o[0]=f2bf(a.x); o[1]=f2bf(a.y); o[2]=f2bf(a.z); o[3]=f2bf(a.w);
    o[4]=f2bf(b.x); o[5]=f2bf(b.y); o[6]=f2bf(b.z); o[7]=f2bf(b.w);
    *(u16x8*)(out + i) = o;
  }
}

// W[K=1024][N=1024] fp32 -> Wt[N][K] bf16
__global__ void transpose_cast(const float* __restrict__ in, u16* __restrict__ out) {
  int t = blockIdx.x * blockDim.x + threadIdx.x;   // 262144 threads
  int n = t & 1023;
  int k4 = (t >> 10) << 2;
  u16x4 o;
#pragma unroll
  for (int j = 0; j < 4; ++j) o[j] = f2bf(in[(size_t)(k4 + j) * 1024 + n]);
  *(u16x4*)(out + (size_t)n * 1024 + k4) = o;
}

// ---------------- GEMM: C[M][N] = A[M][K] @ Bt[N][K]^T + bias ----------------
template<int OUTF32>
__global__ __launch_bounds__(256) void gemm_bias(
    const u16* __restrict__ A, const u16* __restrict__ Bt,
    const float* __restrict__ bias, void* __restrict__ Cp,
    int M, int N, int K)
{
  __shared__ u16 As[128][40];   // pitch 40 -> 80B rows, 16B aligned, <=2-way conflicts
  __shared__ u16 Bs[128][40];
  int tid = threadIdx.x;
  int lane = tid & 63;
  int w = tid >> 6;
  int wr = w >> 1, wc = w & 1;
  int fr = lane & 15, fq = lane >> 4;
  int m0 = blockIdx.x * 128, n0 = blockIdx.y * 128;
  int srow = tid >> 1;
  int scol = (tid & 1) << 4;
  const u16* Ag = A + (size_t)(m0 + srow) * K + scol;
  const u16* Bg = Bt + (size_t)(n0 + srow) * K + scol;
  f32x4 acc[4][4] = {};
  for (int k0 = 0; k0 < K; k0 += 32) {
    u16x8 a0 = *(const u16x8*)(Ag + k0);
    u16x8 a1 = *(const u16x8*)(Ag + k0 + 8);
    u16x8 b0 = *(const u16x8*)(Bg + k0);
    u16x8 b1 = *(const u16x8*)(Bg + k0 + 8);
    __syncthreads();
    *(u16x8*)&As[srow][scol]     = a0;
    *(u16x8*)&As[srow][scol + 8] = a1;
    *(u16x8*)&Bs[srow][scol]     = b0;
    *(u16x8*)&Bs[srow][scol + 8] = b1;
    __syncthreads();
    bf16x8 av[4], bv[4];
#pragma unroll
    for (int m = 0; m < 4; ++m)
      av[m] = *(const bf16x8*)&As[wr*64 + m*16 + fr][fq*8];
#pragma unroll
    for (int n = 0; n < 4; ++n)
      bv[n] = *(const bf16x8*)&Bs[wc*64 + n*16 + fr][fq*8];
#pragma unroll
    for (int m = 0; m < 4; ++m)
#pragma unroll
      for (int n = 0; n < 4; ++n)
        acc[m][n] = __builtin_amdgcn_mfma_f32_16x16x32_bf16(av[m], bv[n], acc[m][n], 0, 0, 0);
  }
#pragma unroll
  for (int m = 0; m < 4; ++m) {
    int row = m0 + wr*64 + m*16 + fq*4;
#pragma unroll
    for (int n = 0; n < 4; ++n) {
      int col = n0 + wc*64 + n*16 + fr;
      float bcol = bias[col];
#pragma unroll
      for (int r = 0; r < 4; ++r) {
        float v = acc[m][n][r] + bcol;
        if (OUTF32) ((float*)Cp)[(size_t)(row + r) * N + col] = v;
        else        ((u16*)Cp)[(size_t)(row + r) * N + col] = f2bf(v);
      }
    }
  }
}

// ---------------- flash attention ----------------
// Q,K,V,O: bf16 [B*S][D], head h occupies cols h*64..h*64+63
__global__ __launch_bounds__(256) void attn_kernel(
    const u16* __restrict__ Qg, const u16* __restrict__ Kg,
    const u16* __restrict__ Vg, u16* __restrict__ Og)
{
  __shared__ u16 Ks[64][72];       // pitch 72 -> 144B rows (16B aligned)
  __shared__ u16 Vt[64][72];       // transposed: Vt[d][kv]
  __shared__ u16 Ps[4][16][72];    // per-wave P tile [q][kv]
  int tid = threadIdx.x;
  int lane = tid & 63;
  int w = tid >> 6;
  int fr = lane & 15, fq = lane >> 4;
  int qt = blockIdx.x;
  int b = blockIdx.y >> 4;
  int h = blockIdx.y & 15;
  const size_t rowbase = (size_t)b * SL;

  // Q fragments (held in registers for whole kernel)
  int qrow = qt*64 + w*16 + fr;
  bf16x8 qa[2];
#pragma unroll
  for (int c = 0; c < 2; ++c)
    qa[c] = *(const bf16x8*)(Qg + (rowbase + qrow) * DM + h*64 + c*32 + fq*8);

  float mrow[4], lrow[4];
  f32x4 o[4] = {};
#pragma unroll
  for (int r = 0; r < 4; ++r) { mrow[r] = -INFINITY; lrow[r] = 0.f; }

  int srow = tid >> 2;
  int schunk = (tid & 3) << 4;

  for (int t = 0; t <= qt; ++t) {
    __syncthreads();
    {
      const u16* kp = Kg + (rowbase + t*64 + srow) * DM + h*64 + schunk;
      u16x8 k0 = *(const u16x8*)kp;
      u16x8 k1 = *(const u16x8*)(kp + 8);
      const u16* vp = Vg + (rowbase + t*64 + srow) * DM + h*64 + schunk;
      u16x8 v0 = *(const u16x8*)vp;
      u16x8 v1 = *(const u16x8*)(vp + 8);
      *(u16x8*)&Ks[srow][schunk]     = k0;
      *(u16x8*)&Ks[srow][schunk + 8] = k1;
#pragma unroll
      for (int j = 0; j < 8; ++j) Vt[schunk + j][srow] = v0[j];
#pragma unroll
      for (int j = 0; j < 8; ++j) Vt[schunk + 8 + j][srow] = v1[j];
    }
    __syncthreads();

    // scores: S[q(16)][kv(64)] in 4 blocks of 16 cols
    f32x4 sb[4];
#pragma unroll
    for (int kb = 0; kb < 4; ++kb) {
      f32x4 s = {};
#pragma unroll
      for (int c = 0; c < 2; ++c) {
        bf16x8 kf = *(const bf16x8*)&Ks[kb*16 + fr][c*32 + fq*8];
        s = __builtin_amdgcn_mfma_f32_16x16x32_bf16(qa[c], kf, s, 0, 0, 0);
      }
      sb[kb] = s;
    }
    bool diag = (t == qt);
#pragma unroll
    for (int kb = 0; kb < 4; ++kb)
#pragma unroll
      for (int r = 0; r < 4; ++r) {
        float v = sb[kb][r] * 0.125f;
        if (diag) {
          int qg2 = qt*64 + w*16 + fq*4 + r;
          int kvg = t*64 + kb*16 + fr;
          if (kvg > qg2) v = -INFINITY;
        }
        sb[kb][r] = v;
      }

    float pm[4];
#pragma unroll
    for (int r = 0; r < 4; ++r)
      pm[r] = fmaxf(fmaxf(sb[0][r], sb[1][r]), fmaxf(sb[2][r], sb[3][r]));
#pragma unroll
    for (int mk = 1; mk < 16; mk <<= 1)
#pragma unroll
      for (int r = 0; r < 4; ++r)
        pm[r] = fmaxf(pm[r], __shfl_xor(pm[r], mk, 64));

    float alpha[4], nm[4];
#pragma unroll
    for (int r = 0; r < 4; ++r) {
      nm[r] = fmaxf(mrow[r], pm[r]);
      alpha[r] = expf(mrow[r] - nm[r]);   // -inf start -> alpha = 0
      mrow[r] = nm[r];
    }

    float psum[4] = {0.f, 0.f, 0.f, 0.f};
#pragma unroll
    for (int kb = 0; kb < 4; ++kb)
#pragma unroll
      for (int r = 0; r < 4; ++r) {
        float p = expf(sb[kb][r] - nm[r]);
        psum[r] += p;
        Ps[w][fq*4 + r][kb*16 + fr] = f2bf(p);
      }
#pragma unroll
    for (int mk = 1; mk < 16; mk <<= 1)
#pragma unroll
      for (int r = 0; r < 4; ++r)
        psum[r] += __shfl_xor(psum[r], mk, 64);
#pragma unroll
    for (int r = 0; r < 4; ++r)
      lrow[r] = lrow[r] * alpha[r] + psum[r];
#pragma unroll
    for (int db = 0; db < 4; ++db)
#pragma unroll
      for (int r = 0; r < 4; ++r)
        o[db][r] *= alpha[r];

    // PV: O[q][d] += P[q][kv] V[kv][d]
#pragma unroll
    for (int kc = 0; kc < 2; ++kc) {
      bf16x8 pa = *(const bf16x8*)&Ps[w][fr][kc*32 + fq*8];
#pragma unroll
      for (int db = 0; db < 4; ++db) {
        bf16x8 vb = *(const bf16x8*)&Vt[db*16 + fr][kc*32 + fq*8];
        o[db] = __builtin_amdgcn_mfma_f32_16x16x32_bf16(pa, vb, o[db], 0, 0, 0);
      }
    }
  }

#pragma unroll
  for (int db = 0; db < 4; ++db)
#pragma unroll
    for (int r = 0; r < 4; ++r) {
      float v = o[db][r] / lrow[r];
      int row = qt*64 + w*16 + fq*4 + r;
      Og[(rowbase + row) * DM + h*64 + db*16 + fr] = f2bf(v);
    }
}

// ---------------- launch ----------------
extern "C" void kernel_launch(void* const* d_in, const int* in_sizes, int n_in,
                              void* d_out, int out_size, void* d_ws, size_t ws_size,
                              hipStream_t stream) {
  const float* x  = (const float*)d_in[0];
  const float* wq = (const float*)d_in[1];
  const float* bq = (const float*)d_in[2];
  const float* wk = (const float*)d_in[3];
  const float* bk = (const float*)d_in[4];
  const float* wv = (const float*)d_in[5];
  const float* bv = (const float*)d_in[6];
  const float* wo = (const float*)d_in[7];
  const float* bo = (const float*)d_in[8];

  char* ws = (char*)d_ws;
  u16* Xb  = (u16*)ws;                       // 8 MB; reused as O after projections
  u16* Wqt = (u16*)(ws + 8u*1024*1024);
  u16* Wkt = Wqt + (1u << 20);
  u16* Wvt = Wqt + 2u*(1u << 20);
  u16* Wot = Wqt + 3u*(1u << 20);
  u16* Qb  = (u16*)(ws + 16u*1024*1024);
  u16* Kb  = (u16*)(ws + 24u*1024*1024);
  u16* Vb  = (u16*)(ws + 32u*1024*1024);

  const int nX = BB * SL * DM;               // 4194304
  hipLaunchKernelGGL(cast_bf16, dim3(nX / (256 * 8)), dim3(256), 0, stream, x, Xb, nX);
  hipLaunchKernelGGL(transpose_cast, dim3(1024), dim3(256), 0, stream, wq, Wqt);
  hipLaunchKernelGGL(transpose_cast, dim3(1024), dim3(256), 0, stream, wk, Wkt);
  hipLaunchKernelGGL(transpose_cast, dim3(1024), dim3(256), 0, stream, wv, Wvt);
  hipLaunchKernelGGL(transpose_cast, dim3(1024), dim3(256), 0, stream, wo, Wot);

  dim3 gg(BB * SL / 128, DM / 128);          // (32, 8)
  hipLaunchKernelGGL((gemm_bias<0>), gg, dim3(256), 0, stream, Xb, Wqt, bq, (void*)Qb, BB*SL, DM, DM);
  hipLaunchKernelGGL((gemm_bias<0>), gg, dim3(256), 0, stream, Xb, Wkt, bk, (void*)Kb, BB*SL, DM, DM);
  hipLaunchKernelGGL((gemm_bias<0>), gg, dim3(256), 0, stream, Xb, Wvt, bv, (void*)Vb, BB*SL, DM, DM);

  hipLaunchKernelGGL(attn_kernel, dim3(SL / 64, BB * NH), dim3(256), 0, stream, Qb, Kb, Vb, Xb);

  hipLaunchKernelGGL((gemm_bias<1>), gg, dim3(256), 0, stream, Xb, Wot, bo, d_out, BB*SL, DM, DM);
}

// Round 2
// 184.803 us; speedup vs baseline: 1.6854x; 1.6854x over previous
//
#include <hip/hip_runtime.h>
#include <hip/hip_bf16.h>
#include <math.h>

typedef unsigned short u16;
typedef __bf16 bf16x8 __attribute__((ext_vector_type(8)));
typedef float f32x4 __attribute__((ext_vector_type(4)));
typedef u16 u16x8 __attribute__((ext_vector_type(8)));
typedef u16 u16x4 __attribute__((ext_vector_type(4)));

#define DM 1024
#define NH 16
#define SL 2048
#define BB 2
#define TOK (BB * SL)   // 4096 tokens

__device__ __forceinline__ u16 f2bf(float f) {
  union { float f; unsigned u; } v; v.f = f;
  unsigned r = v.u + 0x7FFFu + ((v.u >> 16) & 1u);
  return (u16)(r >> 16);
}

__device__ __forceinline__ float fexp2(float x) {
  float r; asm("v_exp_f32 %0, %1" : "=v"(r) : "v"(x)); return r;
}

typedef __attribute__((address_space(1))) const unsigned GU;
typedef __attribute__((address_space(3))) unsigned LU;
#define GLOAD16(g, l) __builtin_amdgcn_global_load_lds((GU*)(g), (LU*)(l), 16, 0, 0)

// ---------------- conversion kernels ----------------
__global__ void cast_bf16(const float* __restrict__ in, u16* __restrict__ out, int n) {
  int i = (blockIdx.x * blockDim.x + threadIdx.x) * 8;
  if (i + 8 <= n) {
    float4 a = *(const float4*)(in + i);
    float4 b = *(const float4*)(in + i + 4);
    u16x8 o;
    o[0]=f2bf(a.x); o[1]=f2bf(a.y); o[2]=f2bf(a.z); o[3]=f2bf(a.w);
    o[4]=f2bf(b.x); o[5]=f2bf(b.y); o[6]=f2bf(b.z); o[7]=f2bf(b.w);
    *(u16x8*)(out + i) = o;
  }
}

// W[K=1024][N=1024] fp32 -> Wt[N][K] bf16
__global__ void transpose_cast(const float* __restrict__ in, u16* __restrict__ out) {
  int t = blockIdx.x * blockDim.x + threadIdx.x;
  int n = t & 1023;
  int k4 = (t >> 10) << 2;
  u16x4 o;
#pragma unroll
  for (int j = 0; j < 4; ++j) o[j] = f2bf(in[(size_t)(k4 + j) * 1024 + n]);
  *(u16x4*)(out + (size_t)n * 1024 + k4) = o;
}

// ---------------- GEMM  C[M][N] = A[M][K] @ Bt[N][K]^T + bias ----------------
// BM=64, BN=128, BK=64, 256 threads (4 waves, wave w owns cols w*32..w*32+31).
// MODE 0: fused QKV (Bt is stacked [3072][1024]); Q,K written bf16 row-major,
//         V written TRANSPOSED to Vto[d_model][token].
// MODE 1: output projection, f32 out.
template<int MODE>
__global__ __launch_bounds__(256) void gemm_qkv(
    const u16* __restrict__ A, const u16* __restrict__ Bt,
    const float* __restrict__ b0, const float* __restrict__ b1,
    const float* __restrict__ b2,
    u16* __restrict__ Qo, u16* __restrict__ Ko, u16* __restrict__ Vto,
    float* __restrict__ Fo)
{
  __shared__ u16 As[2][64 * 64];
  __shared__ u16 Bs[2][128 * 64];
  const int tid = threadIdx.x, lane = tid & 63, w = tid >> 6;
  const int fr = lane & 15, fq = lane >> 4;
  const int m0 = blockIdx.x * 64;
  const int n0 = blockIdx.y * 128;
  f32x4 acc[4][2] = {};

  auto stage = [&](int buf, int k0) {
#pragma unroll
    for (int i = 0; i < 2; ++i) {
      int b16 = w * 128 + i * 64 + lane;
      int row = b16 >> 3, ch = b16 & 7;
      GLOAD16(A + (size_t)(m0 + row) * DM + k0 + ((ch ^ (row & 7)) * 8),
              &As[buf][(w * 128 + i * 64) * 8]);
    }
#pragma unroll
    for (int i = 0; i < 4; ++i) {
      int b16 = w * 256 + i * 64 + lane;
      int row = b16 >> 3, ch = b16 & 7;
      GLOAD16(Bt + (size_t)(n0 + row) * DM + k0 + ((ch ^ (row & 7)) * 8),
              &Bs[buf][(w * 256 + i * 64) * 8]);
    }
  };

  stage(0, 0);
  __syncthreads();
  int buf = 0;
  for (int ks = 0; ks < DM / 64; ++ks) {
    if (ks + 1 < DM / 64) stage(buf ^ 1, (ks + 1) * 64);
#pragma unroll
    for (int kk = 0; kk < 2; ++kk) {
      bf16x8 av[4], bv[2];
#pragma unroll
      for (int m = 0; m < 4; ++m) {
        int row = m * 16 + fr;
        av[m] = *(const bf16x8*)&As[buf][row * 64 + (((kk * 4 + fq) ^ (row & 7)) * 8)];
      }
#pragma unroll
      for (int n = 0; n < 2; ++n) {
        int row = w * 32 + n * 16 + fr;
        bv[n] = *(const bf16x8*)&Bs[buf][row * 64 + (((kk * 4 + fq) ^ (row & 7)) * 8)];
      }
#pragma unroll
      for (int m = 0; m < 4; ++m)
#pragma unroll
        for (int n = 0; n < 2; ++n)
          acc[m][n] = __builtin_amdgcn_mfma_f32_16x16x32_bf16(av[m], bv[n], acc[m][n], 0, 0, 0);
    }
    __syncthreads();
    buf ^= 1;
  }

  if (MODE == 0) {
    int nloc = n0 & 1023;
    int mat = n0 >> 10;
    const float* bias = (mat == 0) ? b0 : ((mat == 1) ? b1 : b2);
#pragma unroll
    for (int m = 0; m < 4; ++m) {
      int row = m0 + m * 16 + fq * 4;
#pragma unroll
      for (int n = 0; n < 2; ++n) {
        int col = nloc + w * 32 + n * 16 + fr;
        float bc = bias[col];
        if (mat == 2) {
          u16x4 v4;
#pragma unroll
          for (int r = 0; r < 4; ++r) v4[r] = f2bf(acc[m][n][r] + bc);
          *(u16x4*)(Vto + (size_t)col * TOK + row) = v4;
        } else {
          u16* dst = (mat == 0) ? Qo : Ko;
#pragma unroll
          for (int r = 0; r < 4; ++r)
            dst[(size_t)(row + r) * DM + col] = f2bf(acc[m][n][r] + bc);
        }
      }
    }
  } else {
#pragma unroll
    for (int m = 0; m < 4; ++m) {
      int row = m0 + m * 16 + fq * 4;
#pragma unroll
      for (int n = 0; n < 2; ++n) {
        int col = n0 + w * 32 + n * 16 + fr;
        float bc = b0[col];
#pragma unroll
        for (int r = 0; r < 4; ++r)
          Fo[(size_t)(row + r) * DM + col] = acc[m][n][r] + bc;
      }
    }
  }
}

// ---------------- flash attention ----------------
// Q,K: bf16 [token][1024] (head h = cols h*64..); Vt: bf16 [1024][token].
// Block: 128 q-rows (4 waves x 32), KV tile 64, double-buffered LDS staging.
__global__ __launch_bounds__(256) void attn_kernel(
    const u16* __restrict__ Qg, const u16* __restrict__ Kg,
    const u16* __restrict__ Vt, u16* __restrict__ Og)
{
  __shared__ u16 Ks[2][64 * 64];
  __shared__ u16 Vs[2][64 * 64];
  __shared__ u16 Ps[4][32][72];
  const int tid = threadIdx.x, lane = tid & 63, w = tid >> 6;
  const int fr = lane & 15, fq = lane >> 4;
  const int qt = blockIdx.x;
  const int b = blockIdx.y >> 4, h = blockIdx.y & 15;
  const size_t rowbase = (size_t)b * SL;
  const int nt = 2 * qt + 2;

  bf16x8 qa[2][2];
#pragma unroll
  for (int mr = 0; mr < 2; ++mr) {
    int qrow = qt * 128 + w * 32 + mr * 16 + fr;
#pragma unroll
    for (int c = 0; c < 2; ++c)
      qa[mr][c] = *(const bf16x8*)(Qg + (rowbase + qrow) * DM + h * 64 + c * 32 + fq * 8);
  }
  bf16x8 ones;
#pragma unroll
  for (int j = 0; j < 8; ++j) ones[j] = (__bf16)1.0f;

  float mrow[2][4];
  f32x4 o[2][4] = {};
  f32x4 osum[2] = {};
#pragma unroll
  for (int mr = 0; mr < 2; ++mr)
#pragma unroll
    for (int r = 0; r < 4; ++r) mrow[mr][r] = -INFINITY;

  auto stage = [&](int buf, int t) {
#pragma unroll
    for (int i = 0; i < 2; ++i) {
      int b16 = w * 128 + i * 64 + lane;
      int row = b16 >> 3, ch = b16 & 7;
      GLOAD16(Kg + (rowbase + t * 64 + row) * DM + h * 64 + ((ch ^ (row & 7)) * 8),
              &Ks[buf][(w * 128 + i * 64) * 8]);
    }
#pragma unroll
    for (int i = 0; i < 2; ++i) {
      int b16 = w * 128 + i * 64 + lane;
      int row = b16 >> 3, ch = b16 & 7;   // row = d index within head
      GLOAD16(Vt + (size_t)(h * 64 + row) * TOK + b * SL + t * 64 + ((ch ^ (row & 7)) * 8),
              &Vs[buf][(w * 128 + i * 64) * 8]);
    }
  };

  stage(0, 0);
  __syncthreads();
  int buf = 0;
  const float SCL = 0.18033688f;   // 0.125 * log2(e)

  for (int t = 0; t < nt; ++t) {
    if (t + 1 < nt) stage(buf ^ 1, t + 1);

    bf16x8 kf[4][2];
#pragma unroll
    for (int kb = 0; kb < 4; ++kb) {
      int row = kb * 16 + fr;
#pragma unroll
      for (int c = 0; c < 2; ++c)
        kf[kb][c] = *(const bf16x8*)&Ks[buf][row * 64 + (((c * 4 + fq) ^ (row & 7)) * 8)];
    }
    const bool maskt = (t >= 2 * qt);

#pragma unroll
    for (int mr = 0; mr < 2; ++mr) {
      f32x4 s[4];
#pragma unroll
      for (int kb = 0; kb < 4; ++kb) {
        f32x4 a0 = {};
        a0 = __builtin_amdgcn_mfma_f32_16x16x32_bf16(qa[mr][0], kf[kb][0], a0, 0, 0, 0);
        s[kb] = __builtin_amdgcn_mfma_f32_16x16x32_bf16(qa[mr][1], kf[kb][1], a0, 0, 0, 0);
      }
      float pm0[4];
#pragma unroll
      for (int r = 0; r < 4; ++r) {
        float v0 = s[0][r] * SCL, v1 = s[1][r] * SCL;
        float v2 = s[2][r] * SCL, v3 = s[3][r] * SCL;
        if (maskt) {
          int qg = qt * 128 + w * 32 + mr * 16 + fq * 4 + r;
          int kvb = t * 64 + fr;
          if (kvb      > qg) v0 = -INFINITY;
          if (kvb + 16 > qg) v1 = -INFINITY;
          if (kvb + 32 > qg) v2 = -INFINITY;
          if (kvb + 48 > qg) v3 = -INFINITY;
        }
        s[0][r] = v0; s[1][r] = v1; s[2][r] = v2; s[3][r] = v3;
        pm0[r] = fmaxf(fmaxf(v0, v1), fmaxf(v2, v3));
      }
#pragma unroll
      for (int mk = 1; mk < 16; mk <<= 1)
#pragma unroll
        for (int r = 0; r < 4; ++r)
          pm0[r] = fmaxf(pm0[r], __shfl_xor(pm0[r], mk, 64));
      float alpha[4];
#pragma unroll
      for (int r = 0; r < 4; ++r) {
        float nm = fmaxf(mrow[mr][r], pm0[r]);
        alpha[r] = fexp2(mrow[mr][r] - nm);
        mrow[mr][r] = nm;
      }
#pragma unroll
      for (int kb = 0; kb < 4; ++kb)
#pragma unroll
        for (int r = 0; r < 4; ++r) {
          float p = fexp2(s[kb][r] - mrow[mr][r]);
          Ps[w][mr * 16 + fq * 4 + r][kb * 16 + fr] = f2bf(p);
        }
#pragma unroll
      for (int r = 0; r < 4; ++r) osum[mr][r] *= alpha[r];
#pragma unroll
      for (int db = 0; db < 4; ++db)
#pragma unroll
        for (int r = 0; r < 4; ++r) o[mr][db][r] *= alpha[r];
    }

    // PV
    bf16x8 vb[4][2];
#pragma unroll
    for (int db = 0; db < 4; ++db) {
      int row = db * 16 + fr;
#pragma unroll
      for (int kc = 0; kc < 2; ++kc)
        vb[db][kc] = *(const bf16x8*)&Vs[buf][row * 64 + (((kc * 4 + fq) ^ (row & 7)) * 8)];
    }
#pragma unroll
    for (int mr = 0; mr < 2; ++mr) {
      bf16x8 pa0 = *(const bf16x8*)&Ps[w][mr * 16 + fr][fq * 8];
      bf16x8 pa1 = *(const bf16x8*)&Ps[w][mr * 16 + fr][32 + fq * 8];
#pragma unroll
      for (int db = 0; db < 4; ++db) {
        o[mr][db] = __builtin_amdgcn_mfma_f32_16x16x32_bf16(pa0, vb[db][0], o[mr][db], 0, 0, 0);
        o[mr][db] = __builtin_amdgcn_mfma_f32_16x16x32_bf16(pa1, vb[db][1], o[mr][db], 0, 0, 0);
      }
      osum[mr] = __builtin_amdgcn_mfma_f32_16x16x32_bf16(pa0, ones, osum[mr], 0, 0, 0);
      osum[mr] = __builtin_amdgcn_mfma_f32_16x16x32_bf16(pa1, ones, osum[mr], 0, 0, 0);
    }

    __syncthreads();
    buf ^= 1;
  }

#pragma unroll
  for (int mr = 0; mr < 2; ++mr) {
    int row = qt * 128 + w * 32 + mr * 16 + fq * 4;
#pragma unroll
    for (int db = 0; db < 4; ++db) {
      int col = h * 64 + db * 16 + fr;
#pragma unroll
      for (int r = 0; r < 4; ++r)
        Og[(rowbase + row + r) * DM + col] = f2bf(o[mr][db][r] / osum[mr][r]);
    }
  }
}

// ---------------- launch ----------------
extern "C" void kernel_launch(void* const* d_in, const int* in_sizes, int n_in,
                              void* d_out, int out_size, void* d_ws, size_t ws_size,
                              hipStream_t stream) {
  const float* x  = (const float*)d_in[0];
  const float* wq = (const float*)d_in[1];
  const float* bq = (const float*)d_in[2];
  const float* wk = (const float*)d_in[3];
  const float* bk = (const float*)d_in[4];
  const float* wv = (const float*)d_in[5];
  const float* bv = (const float*)d_in[6];
  const float* wo = (const float*)d_in[7];
  const float* bo = (const float*)d_in[8];

  char* ws = (char*)d_ws;
  u16* Xb  = (u16*)ws;                          // 8 MB  bf16 X; reused as attn output
  u16* Wst = (u16*)(ws + 8u  * 1024 * 1024);    // 6 MB  stacked Wq/Wk/Wv ^T [3072][1024]
  u16* Wot = (u16*)(ws + 14u * 1024 * 1024);    // 2 MB  Wo^T
  u16* Qb  = (u16*)(ws + 16u * 1024 * 1024);    // 8 MB
  u16* Kb  = (u16*)(ws + 24u * 1024 * 1024);    // 8 MB
  u16* VtG = (u16*)(ws + 32u * 1024 * 1024);    // 8 MB  V^T [1024][4096]

  const int nX = TOK * DM;  // 4194304
  hipLaunchKernelGGL(cast_bf16, dim3(nX / (256 * 8)), dim3(256), 0, stream, x, Xb, nX);
  hipLaunchKernelGGL(transpose_cast, dim3(1024), dim3(256), 0, stream, wq, Wst);
  hipLaunchKernelGGL(transpose_cast, dim3(1024), dim3(256), 0, stream, wk, Wst + (1u << 20));
  hipLaunchKernelGGL(transpose_cast, dim3(1024), dim3(256), 0, stream, wv, Wst + 2u * (1u << 20));
  hipLaunchKernelGGL(transpose_cast, dim3(1024), dim3(256), 0, stream, wo, Wot);

  hipLaunchKernelGGL((gemm_qkv<0>), dim3(TOK / 64, 3072 / 128), dim3(256), 0, stream,
                     Xb, Wst, bq, bk, bv, Qb, Kb, VtG, (float*)nullptr);

  hipLaunchKernelGGL(attn_kernel, dim3(SL / 128, BB * NH), dim3(256), 0, stream,
                     Qb, Kb, VtG, Xb);

  hipLaunchKernelGGL((gemm_qkv<1>), dim3(TOK / 64, DM / 128), dim3(256), 0, stream,
                     Xb, Wot, bo, (const float*)nullptr, (const float*)nullptr,
                     (u16*)nullptr, (u16*)nullptr, (u16*)nullptr, (float*)d_out);
}

// Round 3
// 155.794 us; speedup vs baseline: 1.9992x; 1.1862x over previous
//
#include <hip/hip_runtime.h>
#include <hip/hip_bf16.h>
#include <math.h>

typedef unsigned short u16;
typedef __bf16 bf16x8 __attribute__((ext_vector_type(8)));
typedef float f32x4 __attribute__((ext_vector_type(4)));
typedef u16 u16x8 __attribute__((ext_vector_type(8)));
typedef u16 u16x4 __attribute__((ext_vector_type(4)));

#define DM 1024
#define NH 16
#define SL 2048
#define BB 2
#define TOK (BB * SL)   // 4096 tokens
#define NTQ (SL / 128)  // 16 q-tiles per (b,h)

__device__ __forceinline__ u16 f2bf(float f) {
  union { float f; unsigned u; } v; v.f = f;
  unsigned r = v.u + 0x7FFFu + ((v.u >> 16) & 1u);
  return (u16)(r >> 16);
}

__device__ __forceinline__ float fexp2(float x) {
  float r; asm("v_exp_f32 %0, %1" : "=v"(r) : "v"(x)); return r;
}

__device__ __forceinline__ unsigned cvtpk(float lo, float hi) {
  unsigned r;
  asm("v_cvt_pk_bf16_f32 %0, %1, %2" : "=v"(r) : "v"(lo), "v"(hi));
  return r;
}

typedef __attribute__((address_space(1))) const unsigned GU;
typedef __attribute__((address_space(3))) unsigned LU;
#define GLOAD16(g, l) __builtin_amdgcn_global_load_lds((GU*)(g), (LU*)(l), 16, 0, 0)

// ---------------- conversion kernels ----------------
__global__ void cast_bf16(const float* __restrict__ in, u16* __restrict__ out, int n) {
  int i = (blockIdx.x * blockDim.x + threadIdx.x) * 8;
  if (i + 8 <= n) {
    float4 a = *(const float4*)(in + i);
    float4 b = *(const float4*)(in + i + 4);
    u16x8 o;
    o[0]=f2bf(a.x); o[1]=f2bf(a.y); o[2]=f2bf(a.z); o[3]=f2bf(a.w);
    o[4]=f2bf(b.x); o[5]=f2bf(b.y); o[6]=f2bf(b.z); o[7]=f2bf(b.w);
    *(u16x8*)(out + i) = o;
  }
}

// W[K=1024][N=1024] fp32 -> Wt[N][K] bf16
__global__ void transpose_cast(const float* __restrict__ in, u16* __restrict__ out) {
  int t = blockIdx.x * blockDim.x + threadIdx.x;
  int n = t & 1023;
  int k4 = (t >> 10) << 2;
  u16x4 o;
#pragma unroll
  for (int j = 0; j < 4; ++j) o[j] = f2bf(in[(size_t)(k4 + j) * 1024 + n]);
  *(u16x4*)(out + (size_t)n * 1024 + k4) = o;
}

// ---------------- GEMM  C[M][N] = A[M][K] @ Bt[N][K]^T + bias ----------------
template<int MODE>
__global__ __launch_bounds__(256) void gemm_qkv(
    const u16* __restrict__ A, const u16* __restrict__ Bt,
    const float* __restrict__ b0, const float* __restrict__ b1,
    const float* __restrict__ b2,
    u16* __restrict__ Qo, u16* __restrict__ Ko, u16* __restrict__ Vto,
    float* __restrict__ Fo)
{
  __shared__ u16 As[2][64 * 64];
  __shared__ u16 Bs[2][128 * 64];
  const int tid = threadIdx.x, lane = tid & 63, w = tid >> 6;
  const int fr = lane & 15, fq = lane >> 4;
  const int m0 = blockIdx.x * 64;
  const int n0 = blockIdx.y * 128;
  f32x4 acc[4][2] = {};

  auto stage = [&](int buf, int k0) {
#pragma unroll
    for (int i = 0; i < 2; ++i) {
      int b16 = w * 128 + i * 64 + lane;
      int row = b16 >> 3, ch = b16 & 7;
      GLOAD16(A + (size_t)(m0 + row) * DM + k0 + ((ch ^ (row & 7)) * 8),
              &As[buf][(w * 128 + i * 64) * 8]);
    }
#pragma unroll
    for (int i = 0; i < 4; ++i) {
      int b16 = w * 256 + i * 64 + lane;
      int row = b16 >> 3, ch = b16 & 7;
      GLOAD16(Bt + (size_t)(n0 + row) * DM + k0 + ((ch ^ (row & 7)) * 8),
              &Bs[buf][(w * 256 + i * 64) * 8]);
    }
  };

  stage(0, 0);
  __syncthreads();
  int buf = 0;
  for (int ks = 0; ks < DM / 64; ++ks) {
    if (ks + 1 < DM / 64) stage(buf ^ 1, (ks + 1) * 64);
#pragma unroll
    for (int kk = 0; kk < 2; ++kk) {
      bf16x8 av[4], bv[2];
#pragma unroll
      for (int m = 0; m < 4; ++m) {
        int row = m * 16 + fr;
        av[m] = *(const bf16x8*)&As[buf][row * 64 + (((kk * 4 + fq) ^ (row & 7)) * 8)];
      }
#pragma unroll
      for (int n = 0; n < 2; ++n) {
        int row = w * 32 + n * 16 + fr;
        bv[n] = *(const bf16x8*)&Bs[buf][row * 64 + (((kk * 4 + fq) ^ (row & 7)) * 8)];
      }
#pragma unroll
      for (int m = 0; m < 4; ++m)
#pragma unroll
        for (int n = 0; n < 2; ++n)
          acc[m][n] = __builtin_amdgcn_mfma_f32_16x16x32_bf16(av[m], bv[n], acc[m][n], 0, 0, 0);
    }
    __syncthreads();
    buf ^= 1;
  }

  if (MODE == 0) {
    int nloc = n0 & 1023;
    int mat = n0 >> 10;
    const float* bias = (mat == 0) ? b0 : ((mat == 1) ? b1 : b2);
#pragma unroll
    for (int m = 0; m < 4; ++m) {
      int row = m0 + m * 16 + fq * 4;
#pragma unroll
      for (int n = 0; n < 2; ++n) {
        int col = nloc + w * 32 + n * 16 + fr;
        float bc = bias[col];
        if (mat == 2) {
          u16x4 v4;
#pragma unroll
          for (int r = 0; r < 4; ++r) v4[r] = f2bf(acc[m][n][r] + bc);
          *(u16x4*)(Vto + (size_t)col * TOK + row) = v4;
        } else {
          u16* dst = (mat == 0) ? Qo : Ko;
#pragma unroll
          for (int r = 0; r < 4; ++r)
            dst[(size_t)(row + r) * DM + col] = f2bf(acc[m][n][r] + bc);
        }
      }
    }
  } else {
#pragma unroll
    for (int m = 0; m < 4; ++m) {
      int row = m0 + m * 16 + fq * 4;
#pragma unroll
      for (int n = 0; n < 2; ++n) {
        int col = n0 + w * 32 + n * 16 + fr;
        float bc = b0[col];
#pragma unroll
        for (int r = 0; r < 4; ++r)
          Fo[(size_t)(row + r) * DM + col] = acc[m][n][r] + bc;
      }
    }
  }
}

// ---------------- flash attention (swapped QK^T, in-register softmax) -------
// Q,K: bf16 [token][1024]; Vt: bf16 [1024][token]. 1D grid, longest-qt-first.
// Block: 128 q rows (4 waves x 32), KV tile 64, double-buffered LDS.
// S^T = mfma(K,Q): lane owns q-col = base+fr, 16 kv values (kb*16+fq*4+r).
__global__ __launch_bounds__(256) void attn_kernel(
    const u16* __restrict__ Qg, const u16* __restrict__ Kg,
    const u16* __restrict__ Vt, u16* __restrict__ Og)
{
  __shared__ u16 SM[16384];    // [0,8192): K dbuf, [8192,16384): V dbuf; reused as Tb
  const int tid = threadIdx.x, lane = tid & 63, w = tid >> 6;
  const int fr = lane & 15, fq = lane >> 4;
  const int bid = blockIdx.x;
  const int qt = (NTQ - 1) - (bid >> 5);     // longest first
  const int bh = bid & 31;
  const int b = bh >> 4, h = bh & 15;
  const size_t rowbase = (size_t)b * SL;
  const int nt = 2 * qt + 2;

  bf16x8 qa[2][2];
#pragma unroll
  for (int mr = 0; mr < 2; ++mr) {
    int qrow = qt * 128 + w * 32 + mr * 16 + fr;
#pragma unroll
    for (int c = 0; c < 2; ++c)
      qa[mr][c] = *(const bf16x8*)(Qg + (rowbase + qrow) * DM + h * 64 + c * 32 + fq * 8);
  }

  float mrow[2] = { -INFINITY, -INFINITY };
  float lsum[2] = { 0.f, 0.f };
  f32x4 o[2][4] = {};   // O^T fragments: col=q=fr, row d = db*16+fq*4+r

  auto stage = [&](int buf, int t) {
#pragma unroll
    for (int i = 0; i < 2; ++i) {
      int b16 = w * 128 + i * 64 + lane;
      int row = b16 >> 3, ch = b16 & 7;
      GLOAD16(Kg + (rowbase + t * 64 + row) * DM + h * 64 + ((ch ^ (row & 7)) * 8),
              &SM[buf * 4096 + (w * 128 + i * 64) * 8]);
    }
#pragma unroll
    for (int i = 0; i < 2; ++i) {
      int b16 = w * 128 + i * 64 + lane;
      int row = b16 >> 3, ch = b16 & 7;   // row = d index within head
      GLOAD16(Vt + (size_t)(h * 64 + row) * TOK + b * SL + t * 64 + ((ch ^ (row & 7)) * 8),
              &SM[8192 + buf * 4096 + (w * 128 + i * 64) * 8]);
    }
  };

  stage(0, 0);
  __syncthreads();
  int buf = 0;
  const float SCL = 0.18033688f;   // 0.125 * log2(e)
  const int qg = qt * 128 + w * 32 + fr;   // +mr*16 added per mr

  for (int t = 0; t < nt; ++t) {
    if (t + 1 < nt) stage(buf ^ 1, t + 1);

    // K fragments (A operand): kf[kb][c]
    bf16x8 kf[4][2];
#pragma unroll
    for (int kb = 0; kb < 4; ++kb) {
      int row = kb * 16 + fr;
#pragma unroll
      for (int c = 0; c < 2; ++c)
        kf[kb][c] = *(const bf16x8*)&SM[buf * 4096 + row * 64 + (((c * 4 + fq) ^ (row & 7)) * 8)];
    }
    // V^T fragments (A operand for PV): vf[db][c]
    bf16x8 vf[4][2];
#pragma unroll
    for (int db = 0; db < 4; ++db) {
      int row = db * 16 + fr;
#pragma unroll
      for (int c = 0; c < 2; ++c)
        vf[db][c] = *(const bf16x8*)&SM[8192 + buf * 4096 + row * 64 + (((c * 4 + fq) ^ (row & 7)) * 8)];
    }
    const bool maskt = (t >= 2 * qt);
    const int kvb = t * 64 + fq * 4;   // + kb*16 + r

#pragma unroll
    for (int mr = 0; mr < 2; ++mr) {
      f32x4 st[4];
      __builtin_amdgcn_s_setprio(1);
#pragma unroll
      for (int kb = 0; kb < 4; ++kb) {
        f32x4 s0 = {};
        s0 = __builtin_amdgcn_mfma_f32_16x16x32_bf16(kf[kb][0], qa[mr][0], s0, 0, 0, 0);
        st[kb] = __builtin_amdgcn_mfma_f32_16x16x32_bf16(kf[kb][1], qa[mr][1], st[kb] = s0, 0, 0, 0);
      }
      __builtin_amdgcn_s_setprio(0);

      const int qgm = qg + mr * 16;
#pragma unroll
      for (int kb = 0; kb < 4; ++kb)
#pragma unroll
        for (int r = 0; r < 4; ++r) {
          float v = st[kb][r] * SCL;
          if (maskt && (kvb + kb * 16 + r > qgm)) v = -INFINITY;
          st[kb][r] = v;
        }
      // in-lane max over 16, then reduce across the 4 fq lanes of this q
      float pm = fmaxf(fmaxf(fmaxf(st[0][0], st[0][1]), fmaxf(st[0][2], st[0][3])),
                       fmaxf(fmaxf(st[1][0], st[1][1]), fmaxf(st[1][2], st[1][3])));
      float pm2 = fmaxf(fmaxf(fmaxf(st[2][0], st[2][1]), fmaxf(st[2][2], st[2][3])),
                        fmaxf(fmaxf(st[3][0], st[3][1]), fmaxf(st[3][2], st[3][3])));
      pm = fmaxf(pm, pm2);
      pm = fmaxf(pm, __shfl_xor(pm, 16, 64));
      pm = fmaxf(pm, __shfl_xor(pm, 32, 64));

      float nm = fmaxf(mrow[mr], pm);
      float alpha = fexp2(mrow[mr] - nm);
      mrow[mr] = nm;

      unsigned pk2[4][2];
      float ps = 0.f;
#pragma unroll
      for (int kb = 0; kb < 4; ++kb) {
        float p0 = fexp2(st[kb][0] - nm);
        float p1 = fexp2(st[kb][1] - nm);
        float p2 = fexp2(st[kb][2] - nm);
        float p3 = fexp2(st[kb][3] - nm);
        ps += (p0 + p1) + (p2 + p3);
        pk2[kb][0] = cvtpk(p0, p1);
        pk2[kb][1] = cvtpk(p2, p3);
      }
      lsum[mr] = lsum[mr] * alpha + ps;
#pragma unroll
      for (int db = 0; db < 4; ++db)
#pragma unroll
        for (int r = 0; r < 4; ++r) o[mr][db][r] *= alpha;

      // gather PV B-fragments: lane needs P^T[kv=c*32+fq*8+2j(,+1)][q=fr]
      const int srcA = fr + 32 * (fq & 1);
      const int srcB = srcA + 16;
      const bool losel = (fq < 2);
#pragma unroll
      for (int c = 0; c < 2; ++c) {
        unsigned wA0 = (unsigned)__shfl((int)pk2[2*c][0], srcA, 64);
        unsigned wA1 = (unsigned)__shfl((int)pk2[2*c][1], srcA, 64);
        unsigned wB0 = (unsigned)__shfl((int)pk2[2*c][0], srcB, 64);
        unsigned wB1 = (unsigned)__shfl((int)pk2[2*c][1], srcB, 64);
        unsigned xA0 = (unsigned)__shfl((int)pk2[2*c+1][0], srcA, 64);
        unsigned xA1 = (unsigned)__shfl((int)pk2[2*c+1][1], srcA, 64);
        unsigned xB0 = (unsigned)__shfl((int)pk2[2*c+1][0], srcB, 64);
        unsigned xB1 = (unsigned)__shfl((int)pk2[2*c+1][1], srcB, 64);
        union { unsigned u[4]; bf16x8 v; } bb;
        bb.u[0] = losel ? wA0 : xA0;
        bb.u[1] = losel ? wA1 : xA1;
        bb.u[2] = losel ? wB0 : xB0;
        bb.u[3] = losel ? wB1 : xB1;
        __builtin_amdgcn_s_setprio(1);
#pragma unroll
        for (int db = 0; db < 4; ++db)
          o[mr][db] = __builtin_amdgcn_mfma_f32_16x16x32_bf16(vf[db][c], bb.v, o[mr][db], 0, 0, 0);
        __builtin_amdgcn_s_setprio(0);
      }
    }

    __syncthreads();
    buf ^= 1;
  }

  // epilogue: divide, transpose via LDS, coalesced store
  float inv[2];
#pragma unroll
  for (int mr = 0; mr < 2; ++mr) {
    float L = lsum[mr];
    L += __shfl_xor(L, 16, 64);
    L += __shfl_xor(L, 32, 64);
    inv[mr] = 1.0f / L;
  }
  u16* Tb = &SM[w * 2304];   // per-wave [32][72]
#pragma unroll
  for (int mr = 0; mr < 2; ++mr)
#pragma unroll
    for (int db = 0; db < 4; ++db)
#pragma unroll
      for (int w2 = 0; w2 < 2; ++w2) {
        unsigned pk = cvtpk(o[mr][db][2*w2] * inv[mr], o[mr][db][2*w2+1] * inv[mr]);
        *(unsigned*)&Tb[(mr * 16 + fr) * 72 + db * 16 + fq * 4 + 2 * w2] = pk;
      }
  int rr = lane >> 1, cc = (lane & 1) * 32;
  size_t gbase = (rowbase + qt * 128 + w * 32 + rr) * DM + h * 64 + cc;
#pragma unroll
  for (int i = 0; i < 4; ++i)
    *(u16x8*)(Og + gbase + i * 8) = *(const u16x8*)&Tb[rr * 72 + cc + i * 8];
}

// ---------------- launch ----------------
extern "C" void kernel_launch(void* const* d_in, const int* in_sizes, int n_in,
                              void* d_out, int out_size, void* d_ws, size_t ws_size,
                              hipStream_t stream) {
  const float* x  = (const float*)d_in[0];
  const float* wq = (const float*)d_in[1];
  const float* bq = (const float*)d_in[2];
  const float* wk = (const float*)d_in[3];
  const float* bk = (const float*)d_in[4];
  const float* wv = (const float*)d_in[5];
  const float* bv = (const float*)d_in[6];
  const float* wo = (const float*)d_in[7];
  const float* bo = (const float*)d_in[8];

  char* ws = (char*)d_ws;
  u16* Xb  = (u16*)ws;                          // 8 MB  bf16 X; reused as attn output
  u16* Wst = (u16*)(ws + 8u  * 1024 * 1024);    // 6 MB  stacked Wq/Wk/Wv ^T
  u16* Wot = (u16*)(ws + 14u * 1024 * 1024);    // 2 MB  Wo^T
  u16* Qb  = (u16*)(ws + 16u * 1024 * 1024);    // 8 MB
  u16* Kb  = (u16*)(ws + 24u * 1024 * 1024);    // 8 MB
  u16* VtG = (u16*)(ws + 32u * 1024 * 1024);    // 8 MB  V^T [1024][4096]

  const int nX = TOK * DM;
  hipLaunchKernelGGL(cast_bf16, dim3(nX / (256 * 8)), dim3(256), 0, stream, x, Xb, nX);
  hipLaunchKernelGGL(transpose_cast, dim3(1024), dim3(256), 0, stream, wq, Wst);
  hipLaunchKernelGGL(transpose_cast, dim3(1024), dim3(256), 0, stream, wk, Wst + (1u << 20));
  hipLaunchKernelGGL(transpose_cast, dim3(1024), dim3(256), 0, stream, wv, Wst + 2u * (1u << 20));
  hipLaunchKernelGGL(transpose_cast, dim3(1024), dim3(256), 0, stream, wo, Wot);

  hipLaunchKernelGGL((gemm_qkv<0>), dim3(TOK / 64, 3072 / 128), dim3(256), 0, stream,
                     Xb, Wst, bq, bk, bv, Qb, Kb, VtG, (float*)nullptr);

  hipLaunchKernelGGL(attn_kernel, dim3(NTQ * BB * NH), dim3(256), 0, stream,
                     Qb, Kb, VtG, Xb);

  hipLaunchKernelGGL((gemm_qkv<1>), dim3(TOK / 64, DM / 128), dim3(256), 0, stream,
                     Xb, Wot, bo, (const float*)nullptr, (const float*)nullptr,
                     (u16*)nullptr, (u16*)nullptr, (u16*)nullptr, (float*)d_out);
}

// Round 7
// 148.485 us; speedup vs baseline: 2.0976x; 1.0492x over previous
//
#include <hip/hip_runtime.h>
#include <hip/hip_bf16.h>
#include <math.h>

typedef unsigned short u16;
typedef __bf16 bf16x8 __attribute__((ext_vector_type(8)));
typedef float f32x4 __attribute__((ext_vector_type(4)));
typedef u16 u16x8 __attribute__((ext_vector_type(8)));
typedef u16 u16x4 __attribute__((ext_vector_type(4)));

#define DM 1024
#define NH 16
#define SL 2048
#define BB 2
#define TOK (BB * SL)   // 4096 tokens
#define NTQ (SL / 128)  // 16 q-tiles per (b,h)

__device__ __forceinline__ u16 f2bf(float f) {
  union { float f; unsigned u; } v; v.f = f;
  unsigned r = v.u + 0x7FFFu + ((v.u >> 16) & 1u);
  return (u16)(r >> 16);
}

__device__ __forceinline__ float fexp2(float x) {
  float r; asm("v_exp_f32 %0, %1" : "=v"(r) : "v"(x)); return r;
}

typedef __attribute__((address_space(1))) const unsigned GU;
typedef __attribute__((address_space(3))) unsigned LU;
#define GLOAD16(g, l) __builtin_amdgcn_global_load_lds((GU*)(g), (LU*)(l), 16, 0, 0)

// ---------------- conversion kernels ----------------
__global__ void cast_bf16(const float* __restrict__ in, u16* __restrict__ out, int n) {
  int i = (blockIdx.x * blockDim.x + threadIdx.x) * 8;
  if (i + 8 <= n) {
    float4 a = *(const float4*)(in + i);
    float4 b = *(const float4*)(in + i + 4);
    u16x8 o;
    o[0]=f2bf(a.x); o[1]=f2bf(a.y); o[2]=f2bf(a.z); o[3]=f2bf(a.w);
    o[4]=f2bf(b.x); o[5]=f2bf(b.y); o[6]=f2bf(b.z); o[7]=f2bf(b.w);
    *(u16x8*)(out + i) = o;
  }
}

// 4x W[K=1024][N=1024] fp32 -> Wall[mat][N][K] bf16 via LDS tile transpose
__global__ __launch_bounds__(256) void transpose_cast4(
    const float* __restrict__ w0, const float* __restrict__ w1,
    const float* __restrict__ w2, const float* __restrict__ w3,
    u16* __restrict__ out) {
  __shared__ u16 T[64][72];
  int mat = blockIdx.z;
  const float* in = (mat == 0) ? w0 : (mat == 1) ? w1 : (mat == 2) ? w2 : w3;
  u16* o = out + ((size_t)mat << 20);
  int k0 = blockIdx.x * 64, n0 = blockIdx.y * 64;
  int tid = threadIdx.x;
  int r = tid >> 2;             // k-row within tile
  int c0 = (tid & 3) * 16;      // n-col group
#pragma unroll
  for (int j = 0; j < 16; j += 4) {
    float4 f = *(const float4*)(in + (size_t)(k0 + r) * 1024 + n0 + c0 + j);
    T[c0 + j + 0][r] = f2bf(f.x);
    T[c0 + j + 1][r] = f2bf(f.y);
    T[c0 + j + 2][r] = f2bf(f.z);
    T[c0 + j + 3][r] = f2bf(f.w);
  }
  __syncthreads();
  int n = tid >> 2, k1 = (tid & 3) * 16;
#pragma unroll
  for (int j = 0; j < 16; j += 8)
    *(u16x8*)(o + (size_t)(n0 + n) * 1024 + k0 + k1 + j) = *(const u16x8*)&T[n][k1 + j];
}

// ---------------- GEMM  C[M][N] = A[M][K] @ Bt[N][K]^T + bias ----------------
// m97 structure: 128x128 tile, BK=64, single LDS buffer, 2 barriers/K-step,
// 4 waves each owning a 64x64 quadrant (4x4 16x16 fragments).
template<int MODE>
__global__ __launch_bounds__(256) void gemm_qkv(
    const u16* __restrict__ A, const u16* __restrict__ Bt,
    const float* __restrict__ b0, const float* __restrict__ b1,
    const float* __restrict__ b2,
    u16* __restrict__ Qo, u16* __restrict__ Ko, u16* __restrict__ Vto,
    float* __restrict__ Fo)
{
  __shared__ u16 As[128 * 64];
  __shared__ u16 Bs[128 * 64];
  const int tid = threadIdx.x, lane = tid & 63, w = tid >> 6;
  const int fr = lane & 15, fq = lane >> 4;
  const int wr = w >> 1, wc = w & 1;
  const int m0 = blockIdx.x * 128;
  const int n0 = blockIdx.y * 128;
  f32x4 acc[4][4] = {};

  for (int ks = 0; ks < DM / 64; ++ks) {
    int k0 = ks * 64;
#pragma unroll
    for (int i = 0; i < 4; ++i) {
      int b16 = i * 256 + tid;
      int row = b16 >> 3, ch = b16 & 7;
      GLOAD16(A + (size_t)(m0 + row) * DM + k0 + ((ch ^ (row & 7)) * 8), &As[b16 * 8]);
    }
#pragma unroll
    for (int i = 0; i < 4; ++i) {
      int b16 = i * 256 + tid;
      int row = b16 >> 3, ch = b16 & 7;
      GLOAD16(Bt + (size_t)(n0 + row) * DM + k0 + ((ch ^ (row & 7)) * 8), &Bs[b16 * 8]);
    }
    __syncthreads();   // drains vmcnt -> staged data visible
#pragma unroll
    for (int kk = 0; kk < 2; ++kk) {
      bf16x8 av[4], bv[4];
#pragma unroll
      for (int m = 0; m < 4; ++m) {
        int row = wr * 64 + m * 16 + fr;
        av[m] = *(const bf16x8*)&As[row * 64 + (((kk * 4 + fq) ^ (row & 7)) * 8)];
      }
#pragma unroll
      for (int n = 0; n < 4; ++n) {
        int row = wc * 64 + n * 16 + fr;
        bv[n] = *(const bf16x8*)&Bs[row * 64 + (((kk * 4 + fq) ^ (row & 7)) * 8)];
      }
#pragma unroll
      for (int m = 0; m < 4; ++m)
#pragma unroll
        for (int n = 0; n < 4; ++n)
          acc[m][n] = __builtin_amdgcn_mfma_f32_16x16x32_bf16(av[m], bv[n], acc[m][n], 0, 0, 0);
    }
    __syncthreads();   // all reads done before next stage overwrites
  }

  if (MODE == 0) {
    int nloc = n0 & 1023;
    int mat = n0 >> 10;
    const float* bias = (mat == 0) ? b0 : ((mat == 1) ? b1 : b2);
#pragma unroll
    for (int m = 0; m < 4; ++m) {
      int row = m0 + wr * 64 + m * 16 + fq * 4;
#pragma unroll
      for (int n = 0; n < 4; ++n) {
        int col = nloc + wc * 64 + n * 16 + fr;
        float bc = bias[col];
        if (mat == 2) {
          u16x4 v4;
#pragma unroll
          for (int r = 0; r < 4; ++r) v4[r] = f2bf(acc[m][n][r] + bc);
          *(u16x4*)(Vto + (size_t)col * TOK + row) = v4;
        } else {
          u16* dst = (mat == 0) ? Qo : Ko;
#pragma unroll
          for (int r = 0; r < 4; ++r)
            dst[(size_t)(row + r) * DM + col] = f2bf(acc[m][n][r] + bc);
        }
      }
    }
  } else {
#pragma unroll
    for (int m = 0; m < 4; ++m) {
      int row = m0 + wr * 64 + m * 16 + fq * 4;
#pragma unroll
      for (int n = 0; n < 4; ++n) {
        int col = n0 + wc * 64 + n * 16 + fr;
        float bc = b0[col];
#pragma unroll
        for (int r = 0; r < 4; ++r)
          Fo[(size_t)(row + r) * DM + col] = acc[m][n][r] + bc;
      }
    }
  }
}

// ---------------- flash attention (R3-verified 16x16 body, KV tile 128) ----
// Q,K: bf16 [token][1024]; Vt: bf16 [1024][token]. 4 waves x 32 q-rows.
// S^T = mfma(K,Q): lane owns q-col = fr, kv rows = kb*16 + fq*4 + r.
__global__ __launch_bounds__(256) void attn_kernel(
    const u16* __restrict__ Qg, const u16* __restrict__ Kg,
    const u16* __restrict__ Vt, u16* __restrict__ Og)
{
  __shared__ u16 SM[32768];  // [0,16384) K dbuf (2x 128x64), [16384,32768) V dbuf (2x 64x128)
  const int tid = threadIdx.x, lane = tid & 63, w = tid >> 6;
  const int fr = lane & 15, fq = lane >> 4;
  const int bid = blockIdx.x;
  const int qt = (NTQ - 1) - (bid >> 5);     // longest first
  const int bh = bid & 31;
  const int b = bh >> 4, h = bh & 15;
  const size_t rowbase = (size_t)b * SL;
  const int nt = qt + 1;                     // 128-wide kv tiles

  bf16x8 qa[2][2];
#pragma unroll
  for (int mr = 0; mr < 2; ++mr) {
    int qrow = qt * 128 + w * 32 + mr * 16 + fr;
#pragma unroll
    for (int c = 0; c < 2; ++c)
      qa[mr][c] = *(const bf16x8*)(Qg + (rowbase + qrow) * DM + h * 64 + c * 32 + fq * 8);
  }

  float mrow[2] = { -INFINITY, -INFINITY };
  float lsum[2] = { 0.f, 0.f };
  f32x4 o[2][4] = {};   // O^T frags: col=q=fr, d = db*16 + fq*4 + r

  auto stage = [&](int buf, int t) {
#pragma unroll
    for (int i = 0; i < 4; ++i) {            // K: 128 rows(kv) x 64 d
      int b16 = i * 256 + tid;
      int row = b16 >> 3, ch = b16 & 7;
      GLOAD16(Kg + (rowbase + t * 128 + row) * DM + h * 64 + ((ch ^ (row & 7)) * 8),
              &SM[buf * 8192 + b16 * 8]);
    }
#pragma unroll
    for (int i = 0; i < 4; ++i) {            // V^T: 64 rows(d) x 128 kv
      int b16 = i * 256 + tid;
      int row = b16 >> 4, ch = b16 & 15;
      GLOAD16(Vt + (size_t)(h * 64 + row) * TOK + b * SL + t * 128 + ((ch ^ (row & 15)) * 8),
              &SM[16384 + buf * 8192 + b16 * 8]);
    }
  };

  stage(0, 0);
  __syncthreads();
  int buf = 0;
  const float SCL = 0.18033688f;   // 0.125 * log2(e)
  const int qg = qt * 128 + w * 32 + fr;

  for (int t = 0; t < nt; ++t) {
    if (t + 1 < nt) stage(buf ^ 1, t + 1);
    const bool maskt = (t == qt);

#pragma unroll
    for (int sh = 0; sh < 2; ++sh) {         // two 64-kv sub-passes (R3 body)
      const u16* Kl = &SM[buf * 8192 + sh * 4096];
      const u16* Vl = &SM[16384 + buf * 8192];

      bf16x8 kf[4][2];
#pragma unroll
      for (int kb = 0; kb < 4; ++kb) {
        int row = kb * 16 + fr;
#pragma unroll
        for (int c = 0; c < 2; ++c)
          kf[kb][c] = *(const bf16x8*)&Kl[row * 64 + (((c * 4 + fq) ^ (row & 7)) * 8)];
      }
      bf16x8 vf[4][2];
#pragma unroll
      for (int db = 0; db < 4; ++db) {
        int row = db * 16 + fr;              // row & 15 == fr
#pragma unroll
        for (int c = 0; c < 2; ++c)
          vf[db][c] = *(const bf16x8*)&Vl[row * 128 + (((sh * 8 + c * 4 + fq) ^ fr) * 8)];
      }

#pragma unroll
      for (int mr = 0; mr < 2; ++mr) {
        f32x4 st[4];
        __builtin_amdgcn_s_setprio(1);
#pragma unroll
        for (int kb = 0; kb < 4; ++kb) {
          f32x4 s0 = {};
          s0 = __builtin_amdgcn_mfma_f32_16x16x32_bf16(kf[kb][0], qa[mr][0], s0, 0, 0, 0);
          st[kb] = __builtin_amdgcn_mfma_f32_16x16x32_bf16(kf[kb][1], qa[mr][1], s0, 0, 0, 0);
        }
        __builtin_amdgcn_s_setprio(0);

        const int qgm = qg + mr * 16;
        const int kvb = t * 128 + sh * 64 + fq * 4;
#pragma unroll
        for (int kb = 0; kb < 4; ++kb)
#pragma unroll
          for (int r = 0; r < 4; ++r) {
            float v = st[kb][r] * SCL;
            if (maskt && (kvb + kb * 16 + r > qgm)) v = -INFINITY;
            st[kb][r] = v;
          }
        float pm = fmaxf(fmaxf(fmaxf(st[0][0], st[0][1]), fmaxf(st[0][2], st[0][3])),
                         fmaxf(fmaxf(st[1][0], st[1][1]), fmaxf(st[1][2], st[1][3])));
        float pm2 = fmaxf(fmaxf(fmaxf(st[2][0], st[2][1]), fmaxf(st[2][2], st[2][3])),
                          fmaxf(fmaxf(st[3][0], st[3][1]), fmaxf(st[3][2], st[3][3])));
        pm = fmaxf(pm, pm2);
        pm = fmaxf(pm, __shfl_xor(pm, 16, 64));
        pm = fmaxf(pm, __shfl_xor(pm, 32, 64));

        float nm = fmaxf(mrow[mr], pm);
        float alpha = fexp2(mrow[mr] - nm);
        mrow[mr] = nm;

        unsigned pk2[4][2];
        float ps = 0.f;
#pragma unroll
        for (int kb = 0; kb < 4; ++kb) {
          float p0 = fexp2(st[kb][0] - nm);
          float p1 = fexp2(st[kb][1] - nm);
          float p2 = fexp2(st[kb][2] - nm);
          float p3 = fexp2(st[kb][3] - nm);
          ps += (p0 + p1) + (p2 + p3);
          unsigned lo; asm("v_cvt_pk_bf16_f32 %0, %1, %2" : "=v"(lo) : "v"(p0), "v"(p1));
          unsigned hi2; asm("v_cvt_pk_bf16_f32 %0, %1, %2" : "=v"(hi2) : "v"(p2), "v"(p3));
          pk2[kb][0] = lo; pk2[kb][1] = hi2;
        }
        lsum[mr] = lsum[mr] * alpha + ps;
#pragma unroll
        for (int db = 0; db < 4; ++db)
#pragma unroll
          for (int r = 0; r < 4; ++r) o[mr][db][r] *= alpha;

        // gather PV B-fragments (R3-verified shuffle pattern)
        const int srcA = fr + 32 * (fq & 1);
        const int srcB = srcA + 16;
        const bool losel = (fq < 2);
#pragma unroll
        for (int c = 0; c < 2; ++c) {
          unsigned wA0 = (unsigned)__shfl((int)pk2[2*c][0], srcA, 64);
          unsigned wA1 = (unsigned)__shfl((int)pk2[2*c][1], srcA, 64);
          unsigned wB0 = (unsigned)__shfl((int)pk2[2*c][0], srcB, 64);
          unsigned wB1 = (unsigned)__shfl((int)pk2[2*c][1], srcB, 64);
          unsigned xA0 = (unsigned)__shfl((int)pk2[2*c+1][0], srcA, 64);
          unsigned xA1 = (unsigned)__shfl((int)pk2[2*c+1][1], srcA, 64);
          unsigned xB0 = (unsigned)__shfl((int)pk2[2*c+1][0], srcB, 64);
          unsigned xB1 = (unsigned)__shfl((int)pk2[2*c+1][1], srcB, 64);
          union { unsigned u[4]; bf16x8 v; } bb;
          bb.u[0] = losel ? wA0 : xA0;
          bb.u[1] = losel ? wA1 : xA1;
          bb.u[2] = losel ? wB0 : xB0;
          bb.u[3] = losel ? wB1 : xB1;
          __builtin_amdgcn_s_setprio(1);
#pragma unroll
          for (int db = 0; db < 4; ++db)
            o[mr][db] = __builtin_amdgcn_mfma_f32_16x16x32_bf16(vf[db][c], bb.v, o[mr][db], 0, 0, 0);
          __builtin_amdgcn_s_setprio(0);
        }
      }
    }

    __syncthreads();
    buf ^= 1;
  }

  // epilogue: divide, transpose via LDS, coalesced store (R3 verbatim)
  float inv[2];
#pragma unroll
  for (int mr = 0; mr < 2; ++mr) {
    float L = lsum[mr];
    L += __shfl_xor(L, 16, 64);
    L += __shfl_xor(L, 32, 64);
    inv[mr] = 1.0f / L;
  }
  u16* Tb = &SM[w * 2304];   // per-wave [32][72]
#pragma unroll
  for (int mr = 0; mr < 2; ++mr)
#pragma unroll
    for (int db = 0; db < 4; ++db)
#pragma unroll
      for (int w2 = 0; w2 < 2; ++w2) {
        unsigned pk;
        float plo = o[mr][db][2*w2] * inv[mr], phi = o[mr][db][2*w2+1] * inv[mr];
        asm("v_cvt_pk_bf16_f32 %0, %1, %2" : "=v"(pk) : "v"(plo), "v"(phi));
        *(unsigned*)&Tb[(mr * 16 + fr) * 72 + db * 16 + fq * 4 + 2 * w2] = pk;
      }
  int rr = lane >> 1, cc = (lane & 1) * 32;
  size_t gbase = (rowbase + qt * 128 + w * 32 + rr) * DM + h * 64 + cc;
#pragma unroll
  for (int i = 0; i < 4; ++i)
    *(u16x8*)(Og + gbase + i * 8) = *(const u16x8*)&Tb[rr * 72 + cc + i * 8];
}

// ---------------- launch ----------------
extern "C" void kernel_launch(void* const* d_in, const int* in_sizes, int n_in,
                              void* d_out, int out_size, void* d_ws, size_t ws_size,
                              hipStream_t stream) {
  const float* x  = (const float*)d_in[0];
  const float* wq = (const float*)d_in[1];
  const float* bq = (const float*)d_in[2];
  const float* wk = (const float*)d_in[3];
  const float* bk = (const float*)d_in[4];
  const float* wv = (const float*)d_in[5];
  const float* bv = (const float*)d_in[6];
  const float* wo = (const float*)d_in[7];
  const float* bo = (const float*)d_in[8];

  char* ws = (char*)d_ws;
  u16* Xb   = (u16*)ws;                          // 8 MB  bf16 X; reused as attn output
  u16* Wall = (u16*)(ws + 8u  * 1024 * 1024);    // 8 MB  Wq/Wk/Wv/Wo ^T stacked
  u16* Qb   = (u16*)(ws + 16u * 1024 * 1024);    // 8 MB
  u16* Kb   = (u16*)(ws + 24u * 1024 * 1024);    // 8 MB
  u16* VtG  = (u16*)(ws + 32u * 1024 * 1024);    // 8 MB  V^T [1024][4096]

  const int nX = TOK * DM;
  hipLaunchKernelGGL(cast_bf16, dim3(nX / (256 * 8)), dim3(256), 0, stream, x, Xb, nX);
  hipLaunchKernelGGL(transpose_cast4, dim3(16, 16, 4), dim3(256), 0, stream, wq, wk, wv, wo, Wall);

  hipLaunchKernelGGL((gemm_qkv<0>), dim3(TOK / 128, 3072 / 128), dim3(256), 0, stream,
                     Xb, Wall, bq, bk, bv, Qb, Kb, VtG, (float*)nullptr);

  hipLaunchKernelGGL(attn_kernel, dim3(NTQ * BB * NH), dim3(256), 0, stream,
                     Qb, Kb, VtG, Xb);

  hipLaunchKernelGGL((gemm_qkv<1>), dim3(TOK / 128, DM / 128), dim3(256), 0, stream,
                     Xb, Wall + 3u * (1u << 20), bo, (const float*)nullptr, (const float*)nullptr,
                     (u16*)nullptr, (u16*)nullptr, (u16*)nullptr, (float*)d_out);
}

// Round 8
// 119.842 us; speedup vs baseline: 2.5990x; 1.2390x over previous
//
#include <hip/hip_runtime.h>
#include <hip/hip_bf16.h>
#include <math.h>

typedef unsigned short u16;
typedef __bf16 bf16x8 __attribute__((ext_vector_type(8)));
typedef short s16x4 __attribute__((ext_vector_type(4)));
typedef float f32x4 __attribute__((ext_vector_type(4)));
typedef u16 u16x8 __attribute__((ext_vector_type(8)));
typedef u16 u16x4 __attribute__((ext_vector_type(4)));

#define DM 1024
#define NH 16
#define SL 2048
#define BB 2
#define TOK (BB * SL)   // 4096 tokens

__device__ __forceinline__ u16 f2bf(float f) {
  union { float f; unsigned u; } v; v.f = f;
  unsigned r = v.u + 0x7FFFu + ((v.u >> 16) & 1u);
  return (u16)(r >> 16);
}

__device__ __forceinline__ float fexp2(float x) {
  float r; asm("v_exp_f32 %0, %1" : "=v"(r) : "v"(x)); return r;
}

__device__ __forceinline__ unsigned cvtpk(float lo, float hi) {
  unsigned r;
  asm("v_cvt_pk_bf16_f32 %0, %1, %2" : "=v"(r) : "v"(lo), "v"(hi));
  return r;
}

// PV MFMA: D[16][16] += A[16][16](V^T) * B[16][16](P^T), K=16.
// B-layout (k=(lane>>4)*4+j, col=lane&15) == S^T D-layout -> P feeds directly.
__device__ __forceinline__ f32x4 pv_mfma(s16x4 a, s16x4 b, f32x4 c) {
#if __has_builtin(__builtin_amdgcn_mfma_f32_16x16x16bf16_1k)
  return __builtin_amdgcn_mfma_f32_16x16x16bf16_1k(a, b, c, 0, 0, 0);
#else
  asm("v_mfma_f32_16x16x16_bf16 %0, %1, %2, %0" : "+v"(c) : "v"(a), "v"(b));
  return c;
#endif
}

typedef __attribute__((address_space(1))) const unsigned GU;
typedef __attribute__((address_space(3))) unsigned LU;
#define GLOAD16(g, l) __builtin_amdgcn_global_load_lds((GU*)(g), (LU*)(l), 16, 0, 0)

// ---------------- conversion kernels ----------------
__global__ void cast_bf16(const float* __restrict__ in, u16* __restrict__ out, int n) {
  int i = (blockIdx.x * blockDim.x + threadIdx.x) * 8;
  if (i + 8 <= n) {
    float4 a = *(const float4*)(in + i);
    float4 b = *(const float4*)(in + i + 4);
    u16x8 o;
    o[0]=f2bf(a.x); o[1]=f2bf(a.y); o[2]=f2bf(a.z); o[3]=f2bf(a.w);
    o[4]=f2bf(b.x); o[5]=f2bf(b.y); o[6]=f2bf(b.z); o[7]=f2bf(b.w);
    *(u16x8*)(out + i) = o;
  }
}

// 4x W[K=1024][N=1024] fp32 -> Wall[mat][N][K] bf16 via LDS tile transpose
__global__ __launch_bounds__(256) void transpose_cast4(
    const float* __restrict__ w0, const float* __restrict__ w1,
    const float* __restrict__ w2, const float* __restrict__ w3,
    u16* __restrict__ out) {
  __shared__ u16 T[64][72];
  int mat = blockIdx.z;
  const float* in = (mat == 0) ? w0 : (mat == 1) ? w1 : (mat == 2) ? w2 : w3;
  u16* o = out + ((size_t)mat << 20);
  int k0 = blockIdx.x * 64, n0 = blockIdx.y * 64;
  int tid = threadIdx.x;
  int r = tid >> 2;
  int c0 = (tid & 3) * 16;
#pragma unroll
  for (int j = 0; j < 16; j += 4) {
    float4 f = *(const float4*)(in + (size_t)(k0 + r) * 1024 + n0 + c0 + j);
    T[c0 + j + 0][r] = f2bf(f.x);
    T[c0 + j + 1][r] = f2bf(f.y);
    T[c0 + j + 2][r] = f2bf(f.z);
    T[c0 + j + 3][r] = f2bf(f.w);
  }
  __syncthreads();
  int n = tid >> 2, k1 = (tid & 3) * 16;
#pragma unroll
  for (int j = 0; j < 16; j += 8)
    *(u16x8*)(o + (size_t)(n0 + n) * 1024 + k0 + k1 + j) = *(const u16x8*)&T[n][k1 + j];
}

// ---------------- GEMM  C[M][N] = A[M][K] @ Bt[N][K]^T + bias ----------------
// m97 structure: 128x128 tile, BK=64, single LDS buffer.
// MODE 0: fused QKV; Q is additionally scaled by 0.125*log2(e) (attn fold).
template<int MODE>
__global__ __launch_bounds__(256) void gemm_qkv(
    const u16* __restrict__ A, const u16* __restrict__ Bt,
    const float* __restrict__ b0, const float* __restrict__ b1,
    const float* __restrict__ b2,
    u16* __restrict__ Qo, u16* __restrict__ Ko, u16* __restrict__ Vto,
    float* __restrict__ Fo)
{
  __shared__ u16 As[128 * 64];
  __shared__ u16 Bs[128 * 64];
  const int tid = threadIdx.x, lane = tid & 63, w = tid >> 6;
  const int fr = lane & 15, fq = lane >> 4;
  const int wr = w >> 1, wc = w & 1;
  const int m0 = blockIdx.x * 128;
  const int n0 = blockIdx.y * 128;
  f32x4 acc[4][4] = {};

  for (int ks = 0; ks < DM / 64; ++ks) {
    int k0 = ks * 64;
#pragma unroll
    for (int i = 0; i < 4; ++i) {
      int b16 = i * 256 + tid;
      int row = b16 >> 3, ch = b16 & 7;
      GLOAD16(A + (size_t)(m0 + row) * DM + k0 + ((ch ^ (row & 7)) * 8), &As[b16 * 8]);
    }
#pragma unroll
    for (int i = 0; i < 4; ++i) {
      int b16 = i * 256 + tid;
      int row = b16 >> 3, ch = b16 & 7;
      GLOAD16(Bt + (size_t)(n0 + row) * DM + k0 + ((ch ^ (row & 7)) * 8), &Bs[b16 * 8]);
    }
    __syncthreads();
#pragma unroll
    for (int kk = 0; kk < 2; ++kk) {
      bf16x8 av[4], bv[4];
#pragma unroll
      for (int m = 0; m < 4; ++m) {
        int row = wr * 64 + m * 16 + fr;
        av[m] = *(const bf16x8*)&As[row * 64 + (((kk * 4 + fq) ^ (row & 7)) * 8)];
      }
#pragma unroll
      for (int n = 0; n < 4; ++n) {
        int row = wc * 64 + n * 16 + fr;
        bv[n] = *(const bf16x8*)&Bs[row * 64 + (((kk * 4 + fq) ^ (row & 7)) * 8)];
      }
#pragma unroll
      for (int m = 0; m < 4; ++m)
#pragma unroll
        for (int n = 0; n < 4; ++n)
          acc[m][n] = __builtin_amdgcn_mfma_f32_16x16x32_bf16(av[m], bv[n], acc[m][n], 0, 0, 0);
    }
    __syncthreads();
  }

  if (MODE == 0) {
    int nloc = n0 & 1023;
    int mat = n0 >> 10;
    const float* bias = (mat == 0) ? b0 : ((mat == 1) ? b1 : b2);
    const float scl = (mat == 0) ? 0.18033688f : 1.0f;   // 0.125*log2(e) folded into Q
#pragma unroll
    for (int m = 0; m < 4; ++m) {
      int row = m0 + wr * 64 + m * 16 + fq * 4;
#pragma unroll
      for (int n = 0; n < 4; ++n) {
        int col = nloc + wc * 64 + n * 16 + fr;
        float bc = bias[col];
        if (mat == 2) {
          u16x4 v4;
#pragma unroll
          for (int r = 0; r < 4; ++r) v4[r] = f2bf(acc[m][n][r] + bc);
          *(u16x4*)(Vto + (size_t)col * TOK + row) = v4;
        } else {
          u16* dst = (mat == 0) ? Qo : Ko;
#pragma unroll
          for (int r = 0; r < 4; ++r)
            dst[(size_t)(row + r) * DM + col] = f2bf((acc[m][n][r] + bc) * scl);
        }
      }
    }
  } else {
#pragma unroll
    for (int m = 0; m < 4; ++m) {
      int row = m0 + wr * 64 + m * 16 + fq * 4;
#pragma unroll
      for (int n = 0; n < 4; ++n) {
        int col = n0 + wc * 64 + n * 16 + fr;
        float bc = b0[col];
#pragma unroll
        for (int r = 0; r < 4; ++r)
          Fo[(size_t)(row + r) * DM + col] = acc[m][n][r] + bc;
      }
    }
  }
}

// ---------------- flash attention ----------------
// Q,K: bf16 [token][1024] (Q pre-scaled); Vt: bf16 [1024][token].
// QBLK=64 (4 waves x 16 q), KVBLK=64, double-buffered 32KB LDS, 16 waves/CU.
// QK^T: S^T = mfma_16x16x32(K, Q) -> lane holds S^T[kv=fq*4+r+16kb][q=fr].
// PV: mfma_16x16x16(V^T frag, P) -- P's D-layout IS the K=16 B-layout.
__global__ __launch_bounds__(256, 4) void attn_kernel(
    const u16* __restrict__ Qg, const u16* __restrict__ Kg,
    const u16* __restrict__ Vt, u16* __restrict__ Og)
{
  __shared__ u16 SM[16384];   // [0,8192) K dbuf 2x[64][64]; [8192,16384) V dbuf
  const int tid = threadIdx.x, lane = tid & 63, w = tid >> 6;
  const int fr = lane & 15, fq = lane >> 4;
  const int bid = blockIdx.x;
  const int qt = 31 - (bid >> 5);            // longest first
  const int bh = bid & 31;
  const int b = bh >> 4, h = bh & 15;
  const size_t rowbase = (size_t)b * SL;
  const int nt = qt + 1;

  const int qrow = qt * 64 + w * 16 + fr;
  bf16x8 qa[2];
#pragma unroll
  for (int c = 0; c < 2; ++c)
    qa[c] = *(const bf16x8*)(Qg + (rowbase + qrow) * DM + h * 64 + c * 32 + fq * 8);

  float mrow = -INFINITY, lsum = 0.f;
  f32x4 o[4] = {};   // O^T frags: q=fr, d = db*16 + fq*4 + r

  auto stage = [&](int buf, int t) {
#pragma unroll
    for (int i = 0; i < 2; ++i) {            // K tile [kv=64][d=64]
      int b16 = i * 256 + tid;
      int row = b16 >> 3, ch = b16 & 7;
      GLOAD16(Kg + (rowbase + t * 64 + row) * DM + h * 64 + ((ch ^ (row & 7)) * 8),
              &SM[buf * 4096 + b16 * 8]);
    }
#pragma unroll
    for (int i = 0; i < 2; ++i) {            // V^T tile [d=64][kv=64]
      int b16 = i * 256 + tid;
      int row = b16 >> 3, ch = b16 & 7;
      GLOAD16(Vt + (size_t)(h * 64 + row) * TOK + b * SL + t * 64 + ((ch ^ (row & 7)) * 8),
              &SM[8192 + buf * 4096 + b16 * 8]);
    }
  };

  stage(0, 0);
  __syncthreads();
  int buf = 0;

  for (int t = 0; t < nt; ++t) {
    if (t + 1 < nt) stage(buf ^ 1, t + 1);
    const u16* Kl = &SM[buf * 4096];
    const u16* Vl = &SM[8192 + buf * 4096];

    // QK^T (Q pre-scaled, so st is already in log2-domain units)
    f32x4 st[4];
    __builtin_amdgcn_s_setprio(1);
#pragma unroll
    for (int kb = 0; kb < 4; ++kb) {
      int row = kb * 16 + fr;
      bf16x8 kf0 = *(const bf16x8*)&Kl[row * 64 + ((fq ^ (row & 7)) * 8)];
      bf16x8 kf1 = *(const bf16x8*)&Kl[row * 64 + (((4 + fq) ^ (row & 7)) * 8)];
      f32x4 s0 = {};
      s0 = __builtin_amdgcn_mfma_f32_16x16x32_bf16(kf0, qa[0], s0, 0, 0, 0);
      st[kb] = __builtin_amdgcn_mfma_f32_16x16x32_bf16(kf1, qa[1], s0, 0, 0, 0);
    }
    __builtin_amdgcn_s_setprio(0);

    if (t == qt) {                           // causal mask, diagonal tile only
      const int kvb = t * 64 + fq * 4;
#pragma unroll
      for (int kb = 0; kb < 4; ++kb)
#pragma unroll
        for (int r = 0; r < 4; ++r)
          if (kvb + kb * 16 + r > qrow) st[kb][r] = -INFINITY;
    }

    // row max (in-lane 16, then across the 4 fq lanes of this q)
    float pm = st[0][0];
#pragma unroll
    for (int kb = 0; kb < 4; ++kb)
#pragma unroll
      for (int r = 0; r < 4; ++r) pm = fmaxf(pm, st[kb][r]);
    pm = fmaxf(pm, __shfl_xor(pm, 16, 64));
    pm = fmaxf(pm, __shfl_xor(pm, 32, 64));

    // T13 defer-max: only rescale when the new tile max grows by > 8
    if (__any(pm > mrow + 8.f)) {
      float nm = fmaxf(mrow, pm);
      float alpha = fexp2(mrow - nm);
      mrow = nm;
      lsum *= alpha;
#pragma unroll
      for (int db = 0; db < 4; ++db)
#pragma unroll
        for (int r = 0; r < 4; ++r) o[db][r] *= alpha;
    }

    // exp + pack; P stays in D-layout == PV B-layout
    unsigned pk2[4][2];
    float ps = 0.f;
#pragma unroll
    for (int kb = 0; kb < 4; ++kb) {
      float p0 = fexp2(st[kb][0] - mrow);
      float p1 = fexp2(st[kb][1] - mrow);
      float p2 = fexp2(st[kb][2] - mrow);
      float p3 = fexp2(st[kb][3] - mrow);
      ps += (p0 + p1) + (p2 + p3);
      pk2[kb][0] = cvtpk(p0, p1);
      pk2[kb][1] = cvtpk(p2, p3);
    }
    lsum += ps;

    // PV: o[db] += V^T[d-block][k-block] * P  (zero cross-lane movement)
    __builtin_amdgcn_s_setprio(1);
#pragma unroll
    for (int kb = 0; kb < 4; ++kb) {
      union { unsigned u[2]; s16x4 s; } bb;
      bb.u[0] = pk2[kb][0]; bb.u[1] = pk2[kb][1];
#pragma unroll
      for (int db = 0; db < 4; ++db) {
        int row = db * 16 + fr;
        s16x4 vfr = *(const s16x4*)&Vl[row * 64 + (((kb * 2 + (fq >> 1)) ^ (row & 7)) * 8) + ((fq & 1) * 4)];
        o[db] = pv_mfma(vfr, bb.s, o[db]);
      }
    }
    __builtin_amdgcn_s_setprio(0);

    __syncthreads();
    buf ^= 1;
  }

  // epilogue: reduce l across fq lanes, divide, transpose via LDS, store
  float L = lsum;
  L += __shfl_xor(L, 16, 64);
  L += __shfl_xor(L, 32, 64);
  float inv = 1.0f / L;

  u16* Tb = &SM[w * 1152];   // per-wave [16][72]
#pragma unroll
  for (int db = 0; db < 4; ++db)
#pragma unroll
    for (int w2 = 0; w2 < 2; ++w2) {
      unsigned pk = cvtpk(o[db][2 * w2] * inv, o[db][2 * w2 + 1] * inv);
      *(unsigned*)&Tb[fr * 72 + db * 16 + fq * 4 + 2 * w2] = pk;
    }
  int rr = lane >> 2, cc = (lane & 3) * 16;
  size_t gbase = (rowbase + qt * 64 + w * 16 + rr) * DM + h * 64 + cc;
#pragma unroll
  for (int j = 0; j < 2; ++j)
    *(u16x8*)(Og + gbase + j * 8) = *(const u16x8*)&Tb[rr * 72 + cc + j * 8];
}

// ---------------- launch ----------------
extern "C" void kernel_launch(void* const* d_in, const int* in_sizes, int n_in,
                              void* d_out, int out_size, void* d_ws, size_t ws_size,
                              hipStream_t stream) {
  const float* x  = (const float*)d_in[0];
  const float* wq = (const float*)d_in[1];
  const float* bq = (const float*)d_in[2];
  const float* wk = (const float*)d_in[3];
  const float* bk = (const float*)d_in[4];
  const float* wv = (const float*)d_in[5];
  const float* bv = (const float*)d_in[6];
  const float* wo = (const float*)d_in[7];
  const float* bo = (const float*)d_in[8];

  char* ws = (char*)d_ws;
  u16* Xb   = (u16*)ws;                          // 8 MB  bf16 X; reused as attn output
  u16* Wall = (u16*)(ws + 8u  * 1024 * 1024);    // 8 MB  Wq/Wk/Wv/Wo ^T stacked
  u16* Qb   = (u16*)(ws + 16u * 1024 * 1024);    // 8 MB
  u16* Kb   = (u16*)(ws + 24u * 1024 * 1024);    // 8 MB
  u16* VtG  = (u16*)(ws + 32u * 1024 * 1024);    // 8 MB  V^T [1024][4096]

  const int nX = TOK * DM;
  hipLaunchKernelGGL(cast_bf16, dim3(nX / (256 * 8)), dim3(256), 0, stream, x, Xb, nX);
  hipLaunchKernelGGL(transpose_cast4, dim3(16, 16, 4), dim3(256), 0, stream, wq, wk, wv, wo, Wall);

  hipLaunchKernelGGL((gemm_qkv<0>), dim3(TOK / 128, 3072 / 128), dim3(256), 0, stream,
                     Xb, Wall, bq, bk, bv, Qb, Kb, VtG, (float*)nullptr);

  hipLaunchKernelGGL(attn_kernel, dim3(32 * BB * NH), dim3(256), 0, stream,
                     Qb, Kb, VtG, Xb);

  hipLaunchKernelGGL((gemm_qkv<1>), dim3(TOK / 128, DM / 128), dim3(256), 0, stream,
                     Xb, Wall + 3u * (1u << 20), bo, (const float*)nullptr, (const float*)nullptr,
                     (u16*)nullptr, (u16*)nullptr, (u16*)nullptr, (float*)d_out);
}

// Round 9
// 115.623 us; speedup vs baseline: 2.6938x; 1.0365x over previous
//
#include <hip/hip_runtime.h>
#include <hip/hip_bf16.h>
#include <math.h>

typedef unsigned short u16;
typedef __bf16 bf16x8 __attribute__((ext_vector_type(8)));
typedef short s16x4 __attribute__((ext_vector_type(4)));
typedef float f32x4 __attribute__((ext_vector_type(4)));
typedef u16 u16x8 __attribute__((ext_vector_type(8)));
typedef u16 u16x4 __attribute__((ext_vector_type(4)));

#define DM 1024
#define NH 16
#define SL 2048
#define BB 2
#define TOK (BB * SL)   // 4096 tokens

__device__ __forceinline__ u16 f2bf(float f) {
  union { float f; unsigned u; } v; v.f = f;
  unsigned r = v.u + 0x7FFFu + ((v.u >> 16) & 1u);
  return (u16)(r >> 16);
}

__device__ __forceinline__ float fexp2(float x) {
  float r; asm("v_exp_f32 %0, %1" : "=v"(r) : "v"(x)); return r;
}

__device__ __forceinline__ unsigned cvtpk(float lo, float hi) {
  unsigned r;
  asm("v_cvt_pk_bf16_f32 %0, %1, %2" : "=v"(r) : "v"(lo), "v"(hi));
  return r;
}

// PV MFMA: D[16][16] += A[16][16](V^T) * B[16][16](P^T), K=16.
// B-layout (k=(lane>>4)*4+j, col=lane&15) == S^T D-layout -> P feeds directly.
__device__ __forceinline__ f32x4 pv_mfma(s16x4 a, s16x4 b, f32x4 c) {
#if __has_builtin(__builtin_amdgcn_mfma_f32_16x16x16bf16_1k)
  return __builtin_amdgcn_mfma_f32_16x16x16bf16_1k(a, b, c, 0, 0, 0);
#else
  asm("v_mfma_f32_16x16x16_bf16 %0, %1, %2, %0" : "+v"(c) : "v"(a), "v"(b));
  return c;
#endif
}

typedef __attribute__((address_space(1))) const unsigned GU;
typedef __attribute__((address_space(3))) unsigned LU;
#define GLOAD16(g, l) __builtin_amdgcn_global_load_lds((GU*)(g), (LU*)(l), 16, 0, 0)

// ---------------- conversion kernels ----------------
__global__ void cast_bf16(const float* __restrict__ in, u16* __restrict__ out, int n) {
  int i = (blockIdx.x * blockDim.x + threadIdx.x) * 8;
  if (i + 8 <= n) {
    float4 a = *(const float4*)(in + i);
    float4 b = *(const float4*)(in + i + 4);
    u16x8 o;
    o[0]=f2bf(a.x); o[1]=f2bf(a.y); o[2]=f2bf(a.z); o[3]=f2bf(a.w);
    o[4]=f2bf(b.x); o[5]=f2bf(b.y); o[6]=f2bf(b.z); o[7]=f2bf(b.w);
    *(u16x8*)(out + i) = o;
  }
}

// 4x W[K=1024][N=1024] fp32 -> Wall[mat][N][K] bf16 via LDS tile transpose
__global__ __launch_bounds__(256) void transpose_cast4(
    const float* __restrict__ w0, const float* __restrict__ w1,
    const float* __restrict__ w2, const float* __restrict__ w3,
    u16* __restrict__ out) {
  __shared__ u16 T[64][72];
  int mat = blockIdx.z;
  const float* in = (mat == 0) ? w0 : (mat == 1) ? w1 : (mat == 2) ? w2 : w3;
  u16* o = out + ((size_t)mat << 20);
  int k0 = blockIdx.x * 64, n0 = blockIdx.y * 64;
  int tid = threadIdx.x;
  int r = tid >> 2;
  int c0 = (tid & 3) * 16;
#pragma unroll
  for (int j = 0; j < 16; j += 4) {
    float4 f = *(const float4*)(in + (size_t)(k0 + r) * 1024 + n0 + c0 + j);
    T[c0 + j + 0][r] = f2bf(f.x);
    T[c0 + j + 1][r] = f2bf(f.y);
    T[c0 + j + 2][r] = f2bf(f.z);
    T[c0 + j + 3][r] = f2bf(f.w);
  }
  __syncthreads();
  int n = tid >> 2, k1 = (tid & 3) * 16;
#pragma unroll
  for (int j = 0; j < 16; j += 8)
    *(u16x8*)(o + (size_t)(n0 + n) * 1024 + k0 + k1 + j) = *(const u16x8*)&T[n][k1 + j];
}

// ---------------- GEMM  C[M][N] = A[M][K] @ Bt[N][K]^T + bias ----------------
// 128x128 tile, BK=64, DOUBLE-buffered LDS (64KB), 2-phase overlap:
// issue stage(t+1) -> compute(t) -> barrier (drains prefetch under compute).
// MODE 0: fused QKV; Q additionally scaled by 0.125*log2(e) (attn fold).
template<int MODE>
__global__ __launch_bounds__(256) void gemm_qkv(
    const u16* __restrict__ A, const u16* __restrict__ Bt,
    const float* __restrict__ b0, const float* __restrict__ b1,
    const float* __restrict__ b2,
    u16* __restrict__ Qo, u16* __restrict__ Ko, u16* __restrict__ Vto,
    float* __restrict__ Fo)
{
  __shared__ u16 As[2][128 * 64];
  __shared__ u16 Bs[2][128 * 64];
  const int tid = threadIdx.x, lane = tid & 63, w = tid >> 6;
  const int fr = lane & 15, fq = lane >> 4;
  const int wr = w >> 1, wc = w & 1;
  const int m0 = blockIdx.x * 128;
  const int n0 = blockIdx.y * 128;
  f32x4 acc[4][4] = {};

  auto stage = [&](int buf, int k0) {
#pragma unroll
    for (int i = 0; i < 4; ++i) {
      int b16 = i * 256 + tid;
      int row = b16 >> 3, ch = b16 & 7;
      GLOAD16(A + (size_t)(m0 + row) * DM + k0 + ((ch ^ (row & 7)) * 8), &As[buf][b16 * 8]);
    }
#pragma unroll
    for (int i = 0; i < 4; ++i) {
      int b16 = i * 256 + tid;
      int row = b16 >> 3, ch = b16 & 7;
      GLOAD16(Bt + (size_t)(n0 + row) * DM + k0 + ((ch ^ (row & 7)) * 8), &Bs[buf][b16 * 8]);
    }
  };

  stage(0, 0);
  __syncthreads();
  int buf = 0;
  const int NK = DM / 64;
  for (int ks = 0; ks < NK; ++ks) {
    if (ks + 1 < NK) stage(buf ^ 1, (ks + 1) * 64);   // prefetch in flight across compute
#pragma unroll
    for (int kk = 0; kk < 2; ++kk) {
      bf16x8 av[4], bv[4];
#pragma unroll
      for (int m = 0; m < 4; ++m) {
        int row = wr * 64 + m * 16 + fr;
        av[m] = *(const bf16x8*)&As[buf][row * 64 + (((kk * 4 + fq) ^ (row & 7)) * 8)];
      }
#pragma unroll
      for (int n = 0; n < 4; ++n) {
        int row = wc * 64 + n * 16 + fr;
        bv[n] = *(const bf16x8*)&Bs[buf][row * 64 + (((kk * 4 + fq) ^ (row & 7)) * 8)];
      }
      __builtin_amdgcn_s_setprio(1);
#pragma unroll
      for (int m = 0; m < 4; ++m)
#pragma unroll
        for (int n = 0; n < 4; ++n)
          acc[m][n] = __builtin_amdgcn_mfma_f32_16x16x32_bf16(av[m], bv[n], acc[m][n], 0, 0, 0);
      __builtin_amdgcn_s_setprio(0);
    }
    __syncthreads();   // drains prefetch vmcnt + all ds_reads of buf
    buf ^= 1;
  }

  if (MODE == 0) {
    int nloc = n0 & 1023;
    int mat = n0 >> 10;
    const float* bias = (mat == 0) ? b0 : ((mat == 1) ? b1 : b2);
    const float scl = (mat == 0) ? 0.18033688f : 1.0f;   // 0.125*log2(e) folded into Q
#pragma unroll
    for (int m = 0; m < 4; ++m) {
      int row = m0 + wr * 64 + m * 16 + fq * 4;
#pragma unroll
      for (int n = 0; n < 4; ++n) {
        int col = nloc + wc * 64 + n * 16 + fr;
        float bc = bias[col];
        if (mat == 2) {
          u16x4 v4;
#pragma unroll
          for (int r = 0; r < 4; ++r) v4[r] = f2bf(acc[m][n][r] + bc);
          *(u16x4*)(Vto + (size_t)col * TOK + row) = v4;
        } else {
          u16* dst = (mat == 0) ? Qo : Ko;
#pragma unroll
          for (int r = 0; r < 4; ++r)
            dst[(size_t)(row + r) * DM + col] = f2bf((acc[m][n][r] + bc) * scl);
        }
      }
    }
  } else {
#pragma unroll
    for (int m = 0; m < 4; ++m) {
      int row = m0 + wr * 64 + m * 16 + fq * 4;
#pragma unroll
      for (int n = 0; n < 4; ++n) {
        int col = n0 + wc * 64 + n * 16 + fr;
        float bc = b0[col];
#pragma unroll
        for (int r = 0; r < 4; ++r)
          Fo[(size_t)(row + r) * DM + col] = acc[m][n][r] + bc;
      }
    }
  }
}

// ---------------- flash attention (R8 verbatim, passing) ----------------
__global__ __launch_bounds__(256, 4) void attn_kernel(
    const u16* __restrict__ Qg, const u16* __restrict__ Kg,
    const u16* __restrict__ Vt, u16* __restrict__ Og)
{
  __shared__ u16 SM[16384];   // [0,8192) K dbuf 2x[64][64]; [8192,16384) V dbuf
  const int tid = threadIdx.x, lane = tid & 63, w = tid >> 6;
  const int fr = lane & 15, fq = lane >> 4;
  const int bid = blockIdx.x;
  const int qt = 31 - (bid >> 5);            // longest first
  const int bh = bid & 31;
  const int b = bh >> 4, h = bh & 15;
  const size_t rowbase = (size_t)b * SL;
  const int nt = qt + 1;

  const int qrow = qt * 64 + w * 16 + fr;
  bf16x8 qa[2];
#pragma unroll
  for (int c = 0; c < 2; ++c)
    qa[c] = *(const bf16x8*)(Qg + (rowbase + qrow) * DM + h * 64 + c * 32 + fq * 8);

  float mrow = -INFINITY, lsum = 0.f;
  f32x4 o[4] = {};   // O^T frags: q=fr, d = db*16 + fq*4 + r

  auto stage = [&](int buf, int t) {
#pragma unroll
    for (int i = 0; i < 2; ++i) {            // K tile [kv=64][d=64]
      int b16 = i * 256 + tid;
      int row = b16 >> 3, ch = b16 & 7;
      GLOAD16(Kg + (rowbase + t * 64 + row) * DM + h * 64 + ((ch ^ (row & 7)) * 8),
              &SM[buf * 4096 + b16 * 8]);
    }
#pragma unroll
    for (int i = 0; i < 2; ++i) {            // V^T tile [d=64][kv=64]
      int b16 = i * 256 + tid;
      int row = b16 >> 3, ch = b16 & 7;
      GLOAD16(Vt + (size_t)(h * 64 + row) * TOK + b * SL + t * 64 + ((ch ^ (row & 7)) * 8),
              &SM[8192 + buf * 4096 + b16 * 8]);
    }
  };

  stage(0, 0);
  __syncthreads();
  int buf = 0;

  for (int t = 0; t < nt; ++t) {
    if (t + 1 < nt) stage(buf ^ 1, t + 1);
    const u16* Kl = &SM[buf * 4096];
    const u16* Vl = &SM[8192 + buf * 4096];

    // QK^T (Q pre-scaled, so st is already in log2-domain units)
    f32x4 st[4];
    __builtin_amdgcn_s_setprio(1);
#pragma unroll
    for (int kb = 0; kb < 4; ++kb) {
      int row = kb * 16 + fr;
      bf16x8 kf0 = *(const bf16x8*)&Kl[row * 64 + ((fq ^ (row & 7)) * 8)];
      bf16x8 kf1 = *(const bf16x8*)&Kl[row * 64 + (((4 + fq) ^ (row & 7)) * 8)];
      f32x4 s0 = {};
      s0 = __builtin_amdgcn_mfma_f32_16x16x32_bf16(kf0, qa[0], s0, 0, 0, 0);
      st[kb] = __builtin_amdgcn_mfma_f32_16x16x32_bf16(kf1, qa[1], s0, 0, 0, 0);
    }
    __builtin_amdgcn_s_setprio(0);

    if (t == qt) {                           // causal mask, diagonal tile only
      const int kvb = t * 64 + fq * 4;
#pragma unroll
      for (int kb = 0; kb < 4; ++kb)
#pragma unroll
        for (int r = 0; r < 4; ++r)
          if (kvb + kb * 16 + r > qrow) st[kb][r] = -INFINITY;
    }

    // row max (in-lane 16, then across the 4 fq lanes of this q)
    float pm = st[0][0];
#pragma unroll
    for (int kb = 0; kb < 4; ++kb)
#pragma unroll
      for (int r = 0; r < 4; ++r) pm = fmaxf(pm, st[kb][r]);
    pm = fmaxf(pm, __shfl_xor(pm, 16, 64));
    pm = fmaxf(pm, __shfl_xor(pm, 32, 64));

    // T13 defer-max: only rescale when the new tile max grows by > 8
    if (__any(pm > mrow + 8.f)) {
      float nm = fmaxf(mrow, pm);
      float alpha = fexp2(mrow - nm);
      mrow = nm;
      lsum *= alpha;
#pragma unroll
      for (int db = 0; db < 4; ++db)
#pragma unroll
        for (int r = 0; r < 4; ++r) o[db][r] *= alpha;
    }

    // exp + pack; P stays in D-layout == PV B-layout
    unsigned pk2[4][2];
    float ps = 0.f;
#pragma unroll
    for (int kb = 0; kb < 4; ++kb) {
      float p0 = fexp2(st[kb][0] - mrow);
      float p1 = fexp2(st[kb][1] - mrow);
      float p2 = fexp2(st[kb][2] - mrow);
      float p3 = fexp2(st[kb][3] - mrow);
      ps += (p0 + p1) + (p2 + p3);
      pk2[kb][0] = cvtpk(p0, p1);
      pk2[kb][1] = cvtpk(p2, p3);
    }
    lsum += ps;

    // PV: o[db] += V^T[d-block][k-block] * P  (zero cross-lane movement)
    __builtin_amdgcn_s_setprio(1);
#pragma unroll
    for (int kb = 0; kb < 4; ++kb) {
      union { unsigned u[2]; s16x4 s; } bb;
      bb.u[0] = pk2[kb][0]; bb.u[1] = pk2[kb][1];
#pragma unroll
      for (int db = 0; db < 4; ++db) {
        int row = db * 16 + fr;
        s16x4 vfr = *(const s16x4*)&Vl[row * 64 + (((kb * 2 + (fq >> 1)) ^ (row & 7)) * 8) + ((fq & 1) * 4)];
        o[db] = pv_mfma(vfr, bb.s, o[db]);
      }
    }
    __builtin_amdgcn_s_setprio(0);

    __syncthreads();
    buf ^= 1;
  }

  // epilogue: reduce l across fq lanes, divide, transpose via LDS, store
  float L = lsum;
  L += __shfl_xor(L, 16, 64);
  L += __shfl_xor(L, 32, 64);
  float inv = 1.0f / L;

  u16* Tb = &SM[w * 1152];   // per-wave [16][72]
#pragma unroll
  for (int db = 0; db < 4; ++db)
#pragma unroll
    for (int w2 = 0; w2 < 2; ++w2) {
      unsigned pk = cvtpk(o[db][2 * w2] * inv, o[db][2 * w2 + 1] * inv);
      *(unsigned*)&Tb[fr * 72 + db * 16 + fq * 4 + 2 * w2] = pk;
    }
  int rr = lane >> 2, cc = (lane & 3) * 16;
  size_t gbase = (rowbase + qt * 64 + w * 16 + rr) * DM + h * 64 + cc;
#pragma unroll
  for (int j = 0; j < 2; ++j)
    *(u16x8*)(Og + gbase + j * 8) = *(const u16x8*)&Tb[rr * 72 + cc + j * 8];
}

// ---------------- launch ----------------
extern "C" void kernel_launch(void* const* d_in, const int* in_sizes, int n_in,
                              void* d_out, int out_size, void* d_ws, size_t ws_size,
                              hipStream_t stream) {
  const float* x  = (const float*)d_in[0];
  const float* wq = (const float*)d_in[1];
  const float* bq = (const float*)d_in[2];
  const float* wk = (const float*)d_in[3];
  const float* bk = (const float*)d_in[4];
  const float* wv = (const float*)d_in[5];
  const float* bv = (const float*)d_in[6];
  const float* wo = (const float*)d_in[7];
  const float* bo = (const float*)d_in[8];

  char* ws = (char*)d_ws;
  u16* Xb   = (u16*)ws;                          // 8 MB  bf16 X; reused as attn output
  u16* Wall = (u16*)(ws + 8u  * 1024 * 1024);    // 8 MB  Wq/Wk/Wv/Wo ^T stacked
  u16* Qb   = (u16*)(ws + 16u * 1024 * 1024);    // 8 MB
  u16* Kb   = (u16*)(ws + 24u * 1024 * 1024);    // 8 MB
  u16* VtG  = (u16*)(ws + 32u * 1024 * 1024);    // 8 MB  V^T [1024][4096]

  const int nX = TOK * DM;
  hipLaunchKernelGGL(cast_bf16, dim3(nX / (256 * 8)), dim3(256), 0, stream, x, Xb, nX);
  hipLaunchKernelGGL(transpose_cast4, dim3(16, 16, 4), dim3(256), 0, stream, wq, wk, wv, wo, Wall);

  hipLaunchKernelGGL((gemm_qkv<0>), dim3(TOK / 128, 3072 / 128), dim3(256), 0, stream,
                     Xb, Wall, bq, bk, bv, Qb, Kb, VtG, (float*)nullptr);

  hipLaunchKernelGGL(attn_kernel, dim3(32 * BB * NH), dim3(256), 0, stream,
                     Qb, Kb, VtG, Xb);

  hipLaunchKernelGGL((gemm_qkv<1>), dim3(TOK / 128, DM / 128), dim3(256), 0, stream,
                     Xb, Wall + 3u * (1u << 20), bo, (const float*)nullptr, (const float*)nullptr,
                     (u16*)nullptr, (u16*)nullptr, (u16*)nullptr, (float*)d_out);
}